// Round 2
// baseline (432.809 us; speedup 1.0000x reference)
//
#include <hip/hip_runtime.h>

#define DT_C 0.01f

typedef unsigned short u16;
typedef __bf16 bf8 __attribute__((ext_vector_type(8)));
typedef float f32x4 __attribute__((ext_vector_type(4)));

__device__ __forceinline__ u16 f2bf(float f) {
  unsigned u = __float_as_uint(f);
  unsigned r = (u + 0x7FFFu + ((u >> 16) & 1u)) >> 16;
  return (u16)r;
}
__device__ __forceinline__ float bflo(unsigned w) { return __uint_as_float(w << 16); }
__device__ __forceinline__ float bfhi(unsigned w) { return __uint_as_float(w & 0xFFFF0000u); }
__device__ __forceinline__ float bf2f(u16 v) { return __uint_as_float(((unsigned)v) << 16); }

// ---------------- kernel 1: context encoder -> h (bf16) ----------------
__global__ __launch_bounds__(512) void k_ctxt(const float* __restrict__ xh,
                                              const float* __restrict__ uh,
                                              const float* __restrict__ Wc,
                                              const float* __restrict__ bc,
                                              u16* __restrict__ h_bf) {
  __shared__ float m[96];
  int b = blockIdx.x, t = threadIdx.x;
  if (t < 96) {
    float s = 0.f;
    if (t < 64) {
      const float* p = xh + (size_t)b * 2048 + t;
      for (int tt = 0; tt < 32; ++tt) s += p[tt * 64];
    } else {
      const float* p = uh + (size_t)b * 1024 + (t - 64);
      for (int tt = 0; tt < 32; ++tt) s += p[tt * 32];
    }
    m[t] = s * (1.0f / 32.0f);
  }
  __syncthreads();
  float acc = bc[t];
  #pragma unroll 8
  for (int s = 0; s < 96; ++s) acc += m[s] * Wc[s * 512 + t];
  h_bf[b * 512 + t] = f2bf(tanhf(acc));
}

// ------- kernel 2: head GEMM out[256,N] = h(bf16) @ W(f32, cvt bf16) + b -------
__global__ __launch_bounds__(256) void k_head(const u16* __restrict__ hb,
                                              const float* __restrict__ W,
                                              const float* __restrict__ bias,
                                              float* __restrict__ out, int N) {
  __shared__ __align__(16) u16 Al[256 * 40];
  __shared__ __align__(16) u16 Bl[64 * 40];
  int t = threadIdx.x;
  int n0 = blockIdx.x * 64;
  int w = t >> 6, l = t & 63;
  int r16 = l & 15, kb = (l >> 4) * 8;
  f32x4 acc[4][4];
  #pragma unroll
  for (int i = 0; i < 4; ++i)
    #pragma unroll
    for (int j = 0; j < 4; ++j) acc[i][j] = f32x4{0.f, 0.f, 0.f, 0.f};
  for (int kk = 0; kk < 16; ++kk) {
    int k0 = kk * 32;
    {  // stage A: h rows 256 x 32 (already bf16 in ws)
      int row = t >> 2, kq = t & 3;
      #pragma unroll
      for (int p = 0; p < 4; ++p) {
        int rr = row + 64 * p;
        *(uint4*)(&Al[rr * 40 + kq * 8]) = *(const uint4*)(hb + rr * 512 + k0 + kq * 8);
      }
    }
    {  // stage B: W[k0..+32][n0..+64] -> Bl[n][k] bf16 (transpose + cvt)
      int n = t & 63, kp0 = t >> 6;
      #pragma unroll
      for (int r2 = 0; r2 < 4; ++r2) {
        int kp = kp0 * 4 + r2;
        long k = k0 + kp * 2;
        float f0 = W[k * N + n0 + n];
        float f1 = W[(k + 1) * N + n0 + n];
        unsigned pk = ((unsigned)f2bf(f1) << 16) | (unsigned)f2bf(f0);
        *(unsigned*)(&Bl[n * 40 + kp * 2]) = pk;
      }
    }
    __syncthreads();
    bf8 afr[4], bfr[4];
    #pragma unroll
    for (int mf = 0; mf < 4; ++mf)
      afr[mf] = __builtin_bit_cast(bf8, *(const uint4*)(&Al[(w * 64 + mf * 16 + r16) * 40 + kb]));
    #pragma unroll
    for (int nf = 0; nf < 4; ++nf)
      bfr[nf] = __builtin_bit_cast(bf8, *(const uint4*)(&Bl[(nf * 16 + r16) * 40 + kb]));
    #pragma unroll
    for (int mf = 0; mf < 4; ++mf)
      #pragma unroll
      for (int nf = 0; nf < 4; ++nf)
        acc[mf][nf] = __builtin_amdgcn_mfma_f32_16x16x32_bf16(afr[mf], bfr[nf], acc[mf][nf], 0, 0, 0);
    __syncthreads();
  }
  #pragma unroll
  for (int nf = 0; nf < 4; ++nf) {
    int col = n0 + nf * 16 + r16;
    float bv = bias[col];
    #pragma unroll
    for (int mf = 0; mf < 4; ++mf) {
      int row0 = w * 64 + mf * 16 + (l >> 4) * 4;
      #pragma unroll
      for (int r = 0; r < 4; ++r)
        out[(long)(row0 + r) * N + col] = acc[mf][nf][r] + bv;
    }
  }
}

// ---------------- kernel 3: c_k = B_mat @ u_k  -> Cbf[b][k][i] bf16 ----------------
__global__ __launch_bounds__(256) void k_cprep(const float* __restrict__ Bm,
                                               const float* __restrict__ u_fut,
                                               u16* __restrict__ Cbf) {
  __shared__ float ul[128 * 32];
  int b = blockIdx.x, t = threadIdx.x;
  const float* ub = u_fut + (size_t)b * 4096;
  #pragma unroll
  for (int r = 0; r < 4; ++r)
    *(float4*)(&ul[t * 4 + r * 1024]) = *(const float4*)(ub + t * 4 + r * 1024);
  float br[32];
  const float* bp = Bm + (size_t)b * 8192 + t * 32;
  #pragma unroll
  for (int c4 = 0; c4 < 8; ++c4) {
    float4 v = *(const float4*)(bp + c4 * 4);
    br[c4 * 4] = v.x; br[c4 * 4 + 1] = v.y; br[c4 * 4 + 2] = v.z; br[c4 * 4 + 3] = v.w;
  }
  __syncthreads();
  u16* co = Cbf + (size_t)b * 32768 + t;
  for (int k = 0; k < 128; ++k) {
    float a = 0.f;
    #pragma unroll
    for (int c = 0; c < 32; ++c) a += br[c] * ul[k * 32 + c];
    co[k * 256] = f2bf(a);
  }
}

// ---------------- kernel 4: D2 = 2E + E^2 (E = dt*A_ct), store transposed bf16 ----------------
// 1 WG/batch, 512 thr (8 waves), tile 256x256, K=256 in 8 chunks.
__global__ __launch_bounds__(512) void k_dbl(const float* __restrict__ Act,
                                             u16* __restrict__ D2t) {
  __shared__ __align__(16) u16 Al[256 * 40];
  __shared__ __align__(16) u16 Bl[256 * 40];
  int b = blockIdx.x, t = threadIdx.x;
  const float* A = Act + (size_t)b * 65536;
  int w = t >> 6, l = t & 63, r16 = l & 15, kb = (l >> 4) * 8;
  int ib = (w & 3) * 64, jb = (w >> 2) * 128;
  f32x4 acc[4][8];
  #pragma unroll
  for (int i = 0; i < 4; ++i)
    #pragma unroll
    for (int j = 0; j < 8; ++j) acc[i][j] = f32x4{0.f, 0.f, 0.f, 0.f};
  for (int kk = 0; kk < 8; ++kk) {
    int k0 = kk * 32;
    {  // A stage: rows (E = dt*A), thread covers half-row of 16
      int ai = t >> 1, ah = (t & 1) * 16;
      const float* as = A + (size_t)ai * 256 + k0 + ah;
      u16 tmp[16];
      #pragma unroll
      for (int q = 0; q < 16; q += 4) {
        float4 v = *(const float4*)(as + q);
        tmp[q] = f2bf(v.x * DT_C); tmp[q + 1] = f2bf(v.y * DT_C);
        tmp[q + 2] = f2bf(v.z * DT_C); tmp[q + 3] = f2bf(v.w * DT_C);
      }
      *(uint4*)(&Al[ai * 40 + ah]) = *(uint4*)(tmp);
      *(uint4*)(&Al[ai * 40 + ah + 8]) = *(uint4*)(tmp + 8);
    }
    {  // B stage: cols of E (transposed into Bl[j][m])
      int j = t & 255, mhalf = (t >> 8) * 16;
      u16 tmp[16];
      #pragma unroll
      for (int s = 0; s < 16; ++s)
        tmp[s] = f2bf(A[(size_t)(k0 + mhalf + s) * 256 + j] * DT_C);
      *(uint4*)(&Bl[j * 40 + mhalf]) = *(uint4*)(tmp);
      *(uint4*)(&Bl[j * 40 + mhalf + 8]) = *(uint4*)(tmp + 8);
    }
    __syncthreads();
    bf8 af[4], bfr[8];
    #pragma unroll
    for (int mf = 0; mf < 4; ++mf)
      af[mf] = __builtin_bit_cast(bf8, *(const uint4*)(&Al[(ib + mf * 16 + r16) * 40 + kb]));
    #pragma unroll
    for (int nf = 0; nf < 8; ++nf)
      bfr[nf] = __builtin_bit_cast(bf8, *(const uint4*)(&Bl[(jb + nf * 16 + r16) * 40 + kb]));
    #pragma unroll
    for (int mf = 0; mf < 4; ++mf)
      #pragma unroll
      for (int nf = 0; nf < 8; ++nf)
        acc[mf][nf] = __builtin_amdgcn_mfma_f32_16x16x32_bf16(af[mf], bfr[nf], acc[mf][nf], 0, 0, 0);
    __syncthreads();
  }
  u16* Dp = D2t + (size_t)b * 65536;
  #pragma unroll
  for (int mf = 0; mf < 4; ++mf) {
    int i0 = ib + mf * 16 + (l >> 4) * 4;
    #pragma unroll
    for (int nf = 0; nf < 8; ++nf) {
      int j = jb + nf * 16 + r16;
      float d0 = acc[mf][nf][0] + 2.f * DT_C * A[(size_t)(i0 + 0) * 256 + j];
      float d1 = acc[mf][nf][1] + 2.f * DT_C * A[(size_t)(i0 + 1) * 256 + j];
      float d2 = acc[mf][nf][2] + 2.f * DT_C * A[(size_t)(i0 + 2) * 256 + j];
      float d3 = acc[mf][nf][3] + 2.f * DT_C * A[(size_t)(i0 + 3) * 256 + j];
      uint2 pv;
      pv.x = ((unsigned)f2bf(d1) << 16) | (unsigned)f2bf(d0);
      pv.y = ((unsigned)f2bf(d3) << 16) | (unsigned)f2bf(d2);
      *(uint2*)(&Dp[(size_t)j * 256 + i0]) = pv;
    }
  }
}

// ---------------- kernel 5: Q_i = c_{2i} + c_{2i+1} + E c_{2i}  (f32 out) ----------------
// tile 256 rows x 64 cols (ic), K=256, 4 waves.
__global__ __launch_bounds__(256) void k_comb(const float* __restrict__ Act,
                                              const u16* __restrict__ Cbf,
                                              float* __restrict__ Qf) {
  __shared__ __align__(16) u16 Al[256 * 40];
  __shared__ __align__(16) u16 Bl[64 * 40];
  int b = blockIdx.x, t = threadIdx.x;
  int w = t >> 6, l = t & 63, r16 = l & 15, kb = (l >> 4) * 8;
  const float* A = Act + (size_t)b * 65536;
  const u16* Cb = Cbf + (size_t)b * 32768;
  f32x4 acc[4][4];
  #pragma unroll
  for (int i = 0; i < 4; ++i)
    #pragma unroll
    for (int j = 0; j < 4; ++j) acc[i][j] = f32x4{0.f, 0.f, 0.f, 0.f};
  for (int kk = 0; kk < 8; ++kk) {
    int k0 = kk * 32;
    {  // A stage: row t, 32 u16
      const float* as = A + (size_t)t * 256 + k0;
      u16 tmp[32];
      #pragma unroll
      for (int q = 0; q < 32; q += 4) {
        float4 v = *(const float4*)(as + q);
        tmp[q] = f2bf(v.x * DT_C); tmp[q + 1] = f2bf(v.y * DT_C);
        tmp[q + 2] = f2bf(v.z * DT_C); tmp[q + 3] = f2bf(v.w * DT_C);
      }
      #pragma unroll
      for (int q = 0; q < 4; ++q)
        *(uint4*)(&Al[t * 40 + q * 8]) = *(uint4*)(tmp + q * 8);
    }
    {  // B stage: Bl[ic][m] = c_{2ic}[k0+m]
      int ic = t & 63, q = t >> 6;
      *(uint4*)(&Bl[ic * 40 + q * 8]) = *(const uint4*)(Cb + (size_t)(2 * ic) * 256 + k0 + q * 8);
    }
    __syncthreads();
    bf8 af[4], bfr[4];
    #pragma unroll
    for (int mf = 0; mf < 4; ++mf)
      af[mf] = __builtin_bit_cast(bf8, *(const uint4*)(&Al[(w * 64 + mf * 16 + r16) * 40 + kb]));
    #pragma unroll
    for (int nf = 0; nf < 4; ++nf)
      bfr[nf] = __builtin_bit_cast(bf8, *(const uint4*)(&Bl[(nf * 16 + r16) * 40 + kb]));
    #pragma unroll
    for (int mf = 0; mf < 4; ++mf)
      #pragma unroll
      for (int nf = 0; nf < 4; ++nf)
        acc[mf][nf] = __builtin_amdgcn_mfma_f32_16x16x32_bf16(af[mf], bfr[nf], acc[mf][nf], 0, 0, 0);
    __syncthreads();
  }
  #pragma unroll
  for (int nf = 0; nf < 4; ++nf) {
    int ic = nf * 16 + r16;
    #pragma unroll
    for (int mf = 0; mf < 4; ++mf) {
      int i0 = w * 64 + mf * 16 + (l >> 4) * 4;
      uint2 c0 = *(const uint2*)(Cb + (size_t)(2 * ic) * 256 + i0);
      uint2 c1 = *(const uint2*)(Cb + (size_t)(2 * ic + 1) * 256 + i0);
      float4 st;
      st.x = acc[mf][nf][0] + bflo(c0.x) + bflo(c1.x);
      st.y = acc[mf][nf][1] + bfhi(c0.x) + bfhi(c1.x);
      st.z = acc[mf][nf][2] + bflo(c0.y) + bflo(c1.y);
      st.w = acc[mf][nf][3] + bfhi(c0.y) + bfhi(c1.y);
      *(float4*)(Qf + ((size_t)b * 64 + ic) * 256 + i0) = st;
    }
  }
}

// ---------------- kernel 6: 64-step scan with M^2 = I + D2 ----------------
// z_{2i+2} = z_{2i} + D2 z_{2i} + Q_i ; 1024 threads, 16 j-groups.
__global__ __launch_bounds__(1024) void k_seq(const u16* __restrict__ D2t,
                                              const float* __restrict__ Qf,
                                              const float* __restrict__ x_init,
                                              const float* __restrict__ We,
                                              const float* __restrict__ be,
                                              float* __restrict__ zt,
                                              u16* __restrict__ Zev) {
  __shared__ __align__(16) u16 M[65536];
  __shared__ float zx[256];
  __shared__ float part[16 * 256];
  int b = blockIdx.x, t = threadIdx.x;
  const u16* src = D2t + (size_t)b * 65536;
  #pragma unroll
  for (int r = 0; r < 8; ++r)
    *(uint4*)(&M[t * 64 + r * 8]) = *(const uint4*)(src + t * 64 + r * 8);
  if (t < 256) {
    float z = be[t];
    const float* xi = x_init + b * 64;
    #pragma unroll 8
    for (int s = 0; s < 64; ++s) z += xi[s] * We[s * 256 + t];
    zx[t] = z;
    zt[((size_t)b * 129) * 256 + t] = z;
    Zev[(size_t)b * 16384 + t] = f2bf(z);
  }
  __syncthreads();
  int jg = t >> 6, li = t & 63, i0 = li * 4;
  for (int k = 0; k < 64; ++k) {
    float qv = 0.f;
    if (t < 256) qv = Qf[((size_t)b * 64 + k) * 256 + t];
    float a0 = 0.f, a1 = 0.f, a2 = 0.f, a3 = 0.f;
    #pragma unroll
    for (int jj = 0; jj < 16; ++jj) {
      int j = jg * 16 + jj;
      float s = zx[j];
      uint2 w2 = *(const uint2*)(&M[j * 256 + i0]);
      a0 += s * bflo(w2.x);
      a1 += s * bfhi(w2.x);
      a2 += s * bflo(w2.y);
      a3 += s * bfhi(w2.y);
    }
    *(float4*)(&part[jg * 256 + i0]) = make_float4(a0, a1, a2, a3);
    __syncthreads();
    if (t < 256) {
      float nz = zx[t] + qv;
      #pragma unroll
      for (int g = 0; g < 16; ++g) nz += part[g * 256 + t];
      zx[t] = nz;
      zt[((size_t)b * 129 + 2 * k + 2) * 256 + t] = nz;
      if (k < 63) Zev[(size_t)b * 16384 + (size_t)(k + 1) * 256 + t] = f2bf(nz);
    }
    __syncthreads();
  }
}

// ---------------- kernel 7: odd steps z_{2i+1} = z_{2i} + E z_{2i} + c_{2i} ----------------
__global__ __launch_bounds__(256) void k_down0(const float* __restrict__ Act,
                                               const u16* __restrict__ Zev,
                                               const u16* __restrict__ Cbf,
                                               float* __restrict__ zt) {
  __shared__ __align__(16) u16 Al[256 * 40];
  __shared__ __align__(16) u16 Bl[64 * 40];
  int b = blockIdx.x, t = threadIdx.x;
  int w = t >> 6, l = t & 63, r16 = l & 15, kb = (l >> 4) * 8;
  const float* A = Act + (size_t)b * 65536;
  const u16* Zb = Zev + (size_t)b * 16384;
  const u16* Cb = Cbf + (size_t)b * 32768;
  f32x4 acc[4][4];
  #pragma unroll
  for (int i = 0; i < 4; ++i)
    #pragma unroll
    for (int j = 0; j < 4; ++j) acc[i][j] = f32x4{0.f, 0.f, 0.f, 0.f};
  for (int kk = 0; kk < 8; ++kk) {
    int k0 = kk * 32;
    {
      const float* as = A + (size_t)t * 256 + k0;
      u16 tmp[32];
      #pragma unroll
      for (int q = 0; q < 32; q += 4) {
        float4 v = *(const float4*)(as + q);
        tmp[q] = f2bf(v.x * DT_C); tmp[q + 1] = f2bf(v.y * DT_C);
        tmp[q + 2] = f2bf(v.z * DT_C); tmp[q + 3] = f2bf(v.w * DT_C);
      }
      #pragma unroll
      for (int q = 0; q < 4; ++q)
        *(uint4*)(&Al[t * 40 + q * 8]) = *(uint4*)(tmp + q * 8);
    }
    {
      int ic = t & 63, q = t >> 6;
      *(uint4*)(&Bl[ic * 40 + q * 8]) = *(const uint4*)(Zb + (size_t)ic * 256 + k0 + q * 8);
    }
    __syncthreads();
    bf8 af[4], bfr[4];
    #pragma unroll
    for (int mf = 0; mf < 4; ++mf)
      af[mf] = __builtin_bit_cast(bf8, *(const uint4*)(&Al[(w * 64 + mf * 16 + r16) * 40 + kb]));
    #pragma unroll
    for (int nf = 0; nf < 4; ++nf)
      bfr[nf] = __builtin_bit_cast(bf8, *(const uint4*)(&Bl[(nf * 16 + r16) * 40 + kb]));
    #pragma unroll
    for (int mf = 0; mf < 4; ++mf)
      #pragma unroll
      for (int nf = 0; nf < 4; ++nf)
        acc[mf][nf] = __builtin_amdgcn_mfma_f32_16x16x32_bf16(af[mf], bfr[nf], acc[mf][nf], 0, 0, 0);
    __syncthreads();
  }
  #pragma unroll
  for (int nf = 0; nf < 4; ++nf) {
    int ic = nf * 16 + r16;
    #pragma unroll
    for (int mf = 0; mf < 4; ++mf) {
      int i0 = w * 64 + mf * 16 + (l >> 4) * 4;
      float4 ze = *(const float4*)(zt + ((size_t)b * 129 + 2 * ic) * 256 + i0);
      uint2 cc = *(const uint2*)(Cb + (size_t)(2 * ic) * 256 + i0);
      float4 st;
      st.x = acc[mf][nf][0] + ze.x + bflo(cc.x);
      st.y = acc[mf][nf][1] + ze.y + bfhi(cc.x);
      st.z = acc[mf][nf][2] + ze.z + bflo(cc.y);
      st.w = acc[mf][nf][3] + ze.w + bfhi(cc.y);
      *(float4*)(zt + ((size_t)b * 129 + 2 * ic + 1) * 256 + i0) = st;
    }
  }
}

// ---------------- kernel 8: x_traj = z_traj @ W_dec + b_dec ----------------
__global__ __launch_bounds__(256) void k_dec(const float* __restrict__ z,
                                             const float* __restrict__ Wd,
                                             const float* __restrict__ bd,
                                             float* __restrict__ x) {
  __shared__ __align__(16) u16 Wl[256 * 64];
  __shared__ float zl[16 * 258];
  int t = threadIdx.x;
  long r0 = (long)blockIdx.x * 16;
  #pragma unroll 8
  for (int r = 0; r < 64; ++r) {
    int f = t + 256 * r;
    Wl[f] = f2bf(Wd[f]);
  }
  const float* zsrc = z + r0 * 256;
  #pragma unroll
  for (int r = 0; r < 16; ++r) {
    int f = t + 256 * r;
    int row = f >> 8, n = f & 255;
    zl[row * 258 + n] = zsrc[f];
  }
  __syncthreads();
  int dq = t & 15, rg = t >> 4;
  int d0 = dq * 4;
  float4 bv = *(const float4*)(bd + d0);
  float a0 = bv.x, a1 = bv.y, a2 = bv.z, a3 = bv.w;
  const float* zr = &zl[rg * 258];
  #pragma unroll 8
  for (int n = 0; n < 256; ++n) {
    float zv = zr[n];
    uint2 w2 = *(const uint2*)(&Wl[n * 64 + d0]);
    a0 += zv * bflo(w2.x);
    a1 += zv * bfhi(w2.x);
    a2 += zv * bflo(w2.y);
    a3 += zv * bfhi(w2.y);
  }
  *(float4*)(x + (r0 + rg) * 64 + d0) = make_float4(a0, a1, a2, a3);
}

// ------- kernel 9: z = x @ W_enc + b_enc for x_traj (y=0) and x_gt (y=1) -------
__global__ __launch_bounds__(256) void k_enc(const float* __restrict__ xa,
                                             const float* __restrict__ x_init,
                                             const float* __restrict__ x_fut,
                                             const float* __restrict__ Wen,
                                             const float* __restrict__ ben,
                                             float* __restrict__ z_re,
                                             float* __restrict__ x_gt,
                                             float* __restrict__ z_gt) {
  __shared__ __align__(16) u16 Wl[64 * 256];
  __shared__ float xr[16 * 66];
  int t = threadIdx.x;
  bool gt = (blockIdx.y == 1);
  long r0 = (long)blockIdx.x * 16;
  #pragma unroll 8
  for (int r = 0; r < 64; ++r) {
    int f = t + 256 * r;
    Wl[f] = f2bf(Wen[f]);
  }
  #pragma unroll
  for (int r = 0; r < 4; ++r) {
    int f = t + 256 * r;
    int row = f >> 6, s = f & 63;
    long gr = r0 + row;
    float v;
    if (!gt) {
      v = xa[gr * 64 + s];
    } else {
      long bb = gr / 129, kk = gr - bb * 129;
      v = (kk == 0) ? x_init[bb * 64 + s] : x_fut[(bb * 128 + (kk - 1)) * 64 + s];
      x_gt[gr * 64 + s] = v;
    }
    xr[row * 66 + s] = v;
  }
  __syncthreads();
  int iq = t & 63, rg = t >> 6;
  int i0 = iq * 4;
  float4 bv = *(const float4*)(ben + i0);
  float* zo = gt ? z_gt : z_re;
  #pragma unroll
  for (int rr = 0; rr < 4; ++rr) {
    int row = rg * 4 + rr;
    float a0 = bv.x, a1 = bv.y, a2 = bv.z, a3 = bv.w;
    const float* xp = &xr[row * 66];
    #pragma unroll 8
    for (int s = 0; s < 64; ++s) {
      float xv = xp[s];
      uint2 w2 = *(const uint2*)(&Wl[s * 256 + i0]);
      a0 += xv * bflo(w2.x);
      a1 += xv * bfhi(w2.x);
      a2 += xv * bflo(w2.y);
      a3 += xv * bfhi(w2.y);
    }
    *(float4*)(zo + (r0 + row) * 256 + i0) = make_float4(a0, a1, a2, a3);
  }
}

extern "C" void kernel_launch(void* const* d_in, const int* in_sizes, int n_in,
                              void* d_out, int out_size, void* d_ws, size_t ws_size,
                              hipStream_t stream) {
  const float* xh     = (const float*)d_in[0];
  const float* uh     = (const float*)d_in[1];
  const float* x_init = (const float*)d_in[2];
  const float* x_fut  = (const float*)d_in[3];
  const float* u_fut  = (const float*)d_in[4];
  const float* Wc = (const float*)d_in[6];
  const float* bc = (const float*)d_in[7];
  const float* WA = (const float*)d_in[8];
  const float* bA = (const float*)d_in[9];
  const float* WB = (const float*)d_in[10];
  const float* bB = (const float*)d_in[11];
  const float* We = (const float*)d_in[12];
  const float* be = (const float*)d_in[13];
  const float* Wd = (const float*)d_in[14];
  const float* bd = (const float*)d_in[15];

  float* out    = (float*)d_out;
  float* z_traj = out;                 // [256,129,256]
  float* x_traj = out + 8454144;       // [256,129,64]
  float* A_ct   = out + 10567680;      // [256,256,256]
  float* B_mat  = out + 27344896;      // [256,256,32]
  float* z_re   = out + 29442048;      // [256,129,256]
  float* x_gt   = out + 37896192;      // [256,129,64]
  float* z_gt   = out + 40009728;      // [256,129,256]

  // scratch aliased into not-yet-written outputs (all consumed before their
  // real writers k_enc run):
  u16*   D2t = (u16*)z_re;                    // 33.55MB <= 33.82MB
  u16*   Cbf = (u16*)z_gt;                    // 16.78MB
  float* Qf  = z_gt + 4194304;                // 16.78MB (z_gt total 33.82MB)
  u16*   Zev = (u16*)x_gt;                    // 8.39MB <= 8.45MB
  u16*   h_bf = (u16*)d_ws;                   // 256KB

  hipLaunchKernelGGL(k_ctxt, dim3(256), dim3(512), 0, stream, xh, uh, Wc, bc, h_bf);
  hipLaunchKernelGGL(k_head, dim3(1024), dim3(256), 0, stream, h_bf, WA, bA, A_ct, 65536);
  hipLaunchKernelGGL(k_head, dim3(128), dim3(256), 0, stream, h_bf, WB, bB, B_mat, 8192);
  hipLaunchKernelGGL(k_cprep, dim3(256), dim3(256), 0, stream, B_mat, u_fut, Cbf);
  hipLaunchKernelGGL(k_dbl, dim3(256), dim3(512), 0, stream, A_ct, D2t);
  hipLaunchKernelGGL(k_comb, dim3(256), dim3(256), 0, stream, A_ct, Cbf, Qf);
  hipLaunchKernelGGL(k_seq, dim3(256), dim3(1024), 0, stream, D2t, Qf, x_init, We, be, z_traj, Zev);
  hipLaunchKernelGGL(k_down0, dim3(256), dim3(256), 0, stream, A_ct, Zev, Cbf, z_traj);
  hipLaunchKernelGGL(k_dec, dim3(2064), dim3(256), 0, stream, z_traj, Wd, bd, x_traj);
  hipLaunchKernelGGL(k_enc, dim3(2064, 2), dim3(256), 0, stream, x_traj, x_init, x_fut, We, be, z_re, x_gt, z_gt);
}

// Round 3
// 307.756 us; speedup vs baseline: 1.4063x; 1.4063x over previous
//
#include <hip/hip_runtime.h>

#define DT_C 0.01f

typedef unsigned short u16;
typedef __bf16 bf8 __attribute__((ext_vector_type(8)));
typedef float f32x4 __attribute__((ext_vector_type(4)));

__device__ __forceinline__ u16 f2bf(float f) {
  unsigned u = __float_as_uint(f);
  unsigned r = (u + 0x7FFFu + ((u >> 16) & 1u)) >> 16;
  return (u16)r;
}
__device__ __forceinline__ float bflo(unsigned w) { return __uint_as_float(w << 16); }
__device__ __forceinline__ float bfhi(unsigned w) { return __uint_as_float(w & 0xFFFF0000u); }

// ---------------- kernel 1: context encoder -> h (bf16) ----------------
__global__ __launch_bounds__(512) void k_ctxt(const float* __restrict__ xh,
                                              const float* __restrict__ uh,
                                              const float* __restrict__ Wc,
                                              const float* __restrict__ bc,
                                              u16* __restrict__ h_bf) {
  __shared__ float m[96];
  int b = blockIdx.x, t = threadIdx.x;
  if (t < 96) {
    float s = 0.f;
    if (t < 64) {
      const float* p = xh + (size_t)b * 2048 + t;
      for (int tt = 0; tt < 32; ++tt) s += p[tt * 64];
    } else {
      const float* p = uh + (size_t)b * 1024 + (t - 64);
      for (int tt = 0; tt < 32; ++tt) s += p[tt * 32];
    }
    m[t] = s * (1.0f / 32.0f);
  }
  __syncthreads();
  float acc = bc[t];
  #pragma unroll 8
  for (int s = 0; s < 96; ++s) acc += m[s] * Wc[s * 512 + t];
  h_bf[b * 512 + t] = f2bf(tanhf(acc));
}

// ------- kernel 2: head GEMM out[256,N] = h(bf16) @ W(f32 -> bf16) + b -------
__global__ __launch_bounds__(256) void k_head(const u16* __restrict__ hb,
                                              const float* __restrict__ W,
                                              const float* __restrict__ bias,
                                              float* __restrict__ out, int N) {
  __shared__ __align__(16) u16 Al[256 * 40];
  __shared__ __align__(16) u16 Bl[64 * 40];
  int t = threadIdx.x;
  int n0 = blockIdx.x * 64;
  int w = t >> 6, l = t & 63;
  int r16 = l & 15, kb = (l >> 4) * 8;
  f32x4 acc[4][4];
  #pragma unroll
  for (int i = 0; i < 4; ++i)
    #pragma unroll
    for (int j = 0; j < 4; ++j) acc[i][j] = f32x4{0.f, 0.f, 0.f, 0.f};
  for (int kk = 0; kk < 16; ++kk) {
    int k0 = kk * 32;
    {
      int row = t >> 2, kq = t & 3;
      #pragma unroll
      for (int p = 0; p < 4; ++p) {
        int rr = row + 64 * p;
        *(uint4*)(&Al[rr * 40 + kq * 8]) = *(const uint4*)(hb + rr * 512 + k0 + kq * 8);
      }
    }
    {
      int n = t & 63, kp0 = t >> 6;
      #pragma unroll
      for (int r2 = 0; r2 < 4; ++r2) {
        int kp = kp0 * 4 + r2;
        long k = k0 + kp * 2;
        float f0 = W[k * N + n0 + n];
        float f1 = W[(k + 1) * N + n0 + n];
        unsigned pk = ((unsigned)f2bf(f1) << 16) | (unsigned)f2bf(f0);
        *(unsigned*)(&Bl[n * 40 + kp * 2]) = pk;
      }
    }
    __syncthreads();
    bf8 afr[4], bfr[4];
    #pragma unroll
    for (int mf = 0; mf < 4; ++mf)
      afr[mf] = __builtin_bit_cast(bf8, *(const uint4*)(&Al[(w * 64 + mf * 16 + r16) * 40 + kb]));
    #pragma unroll
    for (int nf = 0; nf < 4; ++nf)
      bfr[nf] = __builtin_bit_cast(bf8, *(const uint4*)(&Bl[(nf * 16 + r16) * 40 + kb]));
    #pragma unroll
    for (int mf = 0; mf < 4; ++mf)
      #pragma unroll
      for (int nf = 0; nf < 4; ++nf)
        acc[mf][nf] = __builtin_amdgcn_mfma_f32_16x16x32_bf16(afr[mf], bfr[nf], acc[mf][nf], 0, 0, 0);
    __syncthreads();
  }
  #pragma unroll
  for (int nf = 0; nf < 4; ++nf) {
    int col = n0 + nf * 16 + r16;
    float bv = bias[col];
    #pragma unroll
    for (int mf = 0; mf < 4; ++mf) {
      int row0 = w * 64 + mf * 16 + (l >> 4) * 4;
      #pragma unroll
      for (int r = 0; r < 4; ++r)
        out[(long)(row0 + r) * N + col] = acc[mf][nf][r] + bv;
    }
  }
}

// ---------------- kernel 3: Wde = Wd @ We, bde = bd @ We + be ----------------
__global__ __launch_bounds__(256) void k_wde(const float* __restrict__ Wd,
                                             const float* __restrict__ We,
                                             const float* __restrict__ bd,
                                             const float* __restrict__ be,
                                             float* __restrict__ Wde,
                                             float* __restrict__ bde) {
  int i = blockIdx.x, t = threadIdx.x;
  if (i < 256) {
    float a = 0.f;
    #pragma unroll 8
    for (int s = 0; s < 64; ++s) a += Wd[i * 64 + s] * We[s * 256 + t];
    Wde[i * 256 + t] = a;
  } else {
    float a = be[t];
    #pragma unroll 8
    for (int s = 0; s < 64; ++s) a += bd[s] * We[s * 256 + t];
    bde[t] = a;
  }
}

// ---------------- kernel 4: c_k = B_mat @ u_k  -> Cf[b][k][i] f32 ----------------
__global__ __launch_bounds__(256) void k_cprep(const float* __restrict__ Bm,
                                               const float* __restrict__ u_fut,
                                               float* __restrict__ Cf) {
  __shared__ float ul[128 * 32];
  int b = blockIdx.x, t = threadIdx.x;
  const float* ub = u_fut + (size_t)b * 4096;
  #pragma unroll
  for (int r = 0; r < 4; ++r)
    *(float4*)(&ul[t * 4 + r * 1024]) = *(const float4*)(ub + t * 4 + r * 1024);
  float br[32];
  const float* bp = Bm + (size_t)b * 8192 + t * 32;
  #pragma unroll
  for (int c4 = 0; c4 < 8; ++c4) {
    float4 v = *(const float4*)(bp + c4 * 4);
    br[c4 * 4] = v.x; br[c4 * 4 + 1] = v.y; br[c4 * 4 + 2] = v.z; br[c4 * 4 + 3] = v.w;
  }
  __syncthreads();
  float* co = Cf + (size_t)b * 32768 + t;
  for (int k = 0; k < 128; ++k) {
    float a = 0.f;
    #pragma unroll
    for (int c = 0; c < 32; ++c) a += br[c] * ul[k * 32 + c];
    co[k * 256] = a;
  }
}

// ---------------- kernel 5: 128-step rollout, M = dt*A held in REGISTERS ----------------
__global__ __launch_bounds__(512) void k_seq(const float* __restrict__ Act,
                                             const float* __restrict__ Cf,
                                             const float* __restrict__ x_init,
                                             const float* __restrict__ We,
                                             const float* __restrict__ be,
                                             float* __restrict__ zt) {
  __shared__ __align__(16) u16 M[65536];     // M[j*256+i], bf16
  __shared__ __align__(16) float zx[256];
  __shared__ __align__(16) float part[8][256];
  int b = blockIdx.x, t = threadIdx.x;
  const float* A = Act + (size_t)b * 65536;
  {  // stage transposed: M[j*256+i] = bf16(dt*A[i*256+j]); write packed i-pairs
    int a = t & 127, jq = t >> 7;
    const float* r0p = A + (size_t)(2 * a) * 256 + jq * 64;
    const float* r1p = r0p + 256;
    unsigned* dst = (unsigned*)M;
    #pragma unroll 4
    for (int jj = 0; jj < 64; jj += 4) {
      float4 v0 = *(const float4*)(r0p + jj);
      float4 v1 = *(const float4*)(r1p + jj);
      int j = jq * 64 + jj;
      dst[(j + 0) * 128 + a] = ((unsigned)f2bf(v1.x * DT_C) << 16) | (unsigned)f2bf(v0.x * DT_C);
      dst[(j + 1) * 128 + a] = ((unsigned)f2bf(v1.y * DT_C) << 16) | (unsigned)f2bf(v0.y * DT_C);
      dst[(j + 2) * 128 + a] = ((unsigned)f2bf(v1.z * DT_C) << 16) | (unsigned)f2bf(v0.z * DT_C);
      dst[(j + 3) * 128 + a] = ((unsigned)f2bf(v1.w * DT_C) << 16) | (unsigned)f2bf(v0.w * DT_C);
    }
  }
  if (t < 256) {  // z0 = We^T x_init + be
    float z = be[t];
    const float* xi = x_init + b * 64;
    #pragma unroll 8
    for (int s = 0; s < 64; ++s) z += xi[s] * We[s * 256 + t];
    zx[t] = z;
    zt[(size_t)b * 33024 + t] = z;
  }
  __syncthreads();
  int jg = t >> 6, li = t & 63, j0 = jg * 32, i0 = li * 4;
  f32x4 m[32];
  #pragma unroll
  for (int jj = 0; jj < 32; ++jj) {
    uint2 w2 = *(const uint2*)((const unsigned*)M + (size_t)(j0 + jj) * 128 + (i0 >> 1));
    m[jj] = f32x4{bflo(w2.x), bfhi(w2.x), bflo(w2.y), bfhi(w2.y)};
  }
  const float* cfb = Cf + (size_t)b * 32768;
  float* ztb = zt + (size_t)b * 33024;
  for (int k = 0; k < 128; ++k) {
    float cq = 0.f;
    if (t < 256) cq = cfb[k * 256 + t];
    float a0 = 0.f, a1 = 0.f, a2 = 0.f, a3 = 0.f;
    #pragma unroll
    for (int q = 0; q < 8; ++q) {
      float4 zv = *(const float4*)(&zx[j0 + q * 4]);
      a0 += zv.x * m[4 * q + 0].x; a1 += zv.x * m[4 * q + 0].y; a2 += zv.x * m[4 * q + 0].z; a3 += zv.x * m[4 * q + 0].w;
      a0 += zv.y * m[4 * q + 1].x; a1 += zv.y * m[4 * q + 1].y; a2 += zv.y * m[4 * q + 1].z; a3 += zv.y * m[4 * q + 1].w;
      a0 += zv.z * m[4 * q + 2].x; a1 += zv.z * m[4 * q + 2].y; a2 += zv.z * m[4 * q + 2].z; a3 += zv.z * m[4 * q + 2].w;
      a0 += zv.w * m[4 * q + 3].x; a1 += zv.w * m[4 * q + 3].y; a2 += zv.w * m[4 * q + 3].z; a3 += zv.w * m[4 * q + 3].w;
    }
    *(float4*)(&part[jg][i0]) = float4{a0, a1, a2, a3};
    __syncthreads();
    if (t < 256) {
      float nz = zx[t] + cq;
      #pragma unroll
      for (int g = 0; g < 8; ++g) nz += part[g][t];
      zx[t] = nz;
      ztb[(size_t)(k + 1) * 256 + t] = nz;
    }
    __syncthreads();
  }
}

// ---- kernel 6: fused decode+re-encode: [x_traj | z_re] = z @ [Wd | Wde] + [bd | bde] ----
__global__ __launch_bounds__(512) void k_decenc(const float* __restrict__ z,
                                                const float* __restrict__ Wd,
                                                const float* __restrict__ bd,
                                                const float* __restrict__ Wde,
                                                const float* __restrict__ bde,
                                                float* __restrict__ x_traj,
                                                float* __restrict__ z_re) {
  __shared__ __align__(16) u16 Al[128 * 40];
  __shared__ __align__(16) u16 Bl[320 * 40];
  int t = threadIdx.x;
  long r0 = (long)blockIdx.x * 128;
  int w = t >> 6, l = t & 63, r16 = l & 15, kb = (l >> 4) * 8;
  int wm = w >> 2, wn = w & 3;
  const float* bsrc = (t < 64) ? (Wd + t) : (Wde + (t - 64));
  int bld = (t < 64) ? 64 : 256;
  f32x4 acc[4][5];
  #pragma unroll
  for (int i = 0; i < 4; ++i)
    #pragma unroll
    for (int j = 0; j < 5; ++j) acc[i][j] = f32x4{0.f, 0.f, 0.f, 0.f};
  for (int kk = 0; kk < 8; ++kk) {
    int k0 = kk * 32;
    {
      int row = t >> 2, kq = t & 3;
      const float* zs = z + (r0 + row) * 256 + k0 + kq * 8;
      float4 v0 = *(const float4*)(zs);
      float4 v1 = *(const float4*)(zs + 4);
      u16 tmp[8];
      tmp[0] = f2bf(v0.x); tmp[1] = f2bf(v0.y); tmp[2] = f2bf(v0.z); tmp[3] = f2bf(v0.w);
      tmp[4] = f2bf(v1.x); tmp[5] = f2bf(v1.y); tmp[6] = f2bf(v1.z); tmp[7] = f2bf(v1.w);
      *(uint4*)(&Al[row * 40 + kq * 8]) = *(uint4*)(tmp);
    }
    if (t < 320) {
      #pragma unroll
      for (int kp = 0; kp < 16; ++kp) {
        int k = k0 + kp * 2;
        float f0 = bsrc[(size_t)k * bld];
        float f1 = bsrc[(size_t)(k + 1) * bld];
        *(unsigned*)(&Bl[t * 40 + kp * 2]) = ((unsigned)f2bf(f1) << 16) | (unsigned)f2bf(f0);
      }
    }
    __syncthreads();
    bf8 af[4], bf[5];
    #pragma unroll
    for (int mf = 0; mf < 4; ++mf)
      af[mf] = __builtin_bit_cast(bf8, *(const uint4*)(&Al[(wm * 64 + mf * 16 + r16) * 40 + kb]));
    #pragma unroll
    for (int nf = 0; nf < 5; ++nf)
      bf[nf] = __builtin_bit_cast(bf8, *(const uint4*)(&Bl[(wn * 80 + nf * 16 + r16) * 40 + kb]));
    #pragma unroll
    for (int mf = 0; mf < 4; ++mf)
      #pragma unroll
      for (int nf = 0; nf < 5; ++nf)
        acc[mf][nf] = __builtin_amdgcn_mfma_f32_16x16x32_bf16(af[mf], bf[nf], acc[mf][nf], 0, 0, 0);
    __syncthreads();
  }
  #pragma unroll
  for (int nf = 0; nf < 5; ++nf) {
    int c = wn * 80 + nf * 16 + r16;
    float bv = (c < 64) ? bd[c] : bde[c - 64];
    #pragma unroll
    for (int mf = 0; mf < 4; ++mf) {
      long row0 = r0 + wm * 64 + mf * 16 + (l >> 4) * 4;
      #pragma unroll
      for (int r = 0; r < 4; ++r) {
        float val = acc[mf][nf][r] + bv;
        if (c < 64) x_traj[(row0 + r) * 64 + c] = val;
        else        z_re[(row0 + r) * 256 + (c - 64)] = val;
      }
    }
  }
}

// ---- kernel 7: assemble x_gt, z_gt = x_gt @ We + be. BM=128, N=256, K=64 ----
__global__ __launch_bounds__(512) void k_gt(const float* __restrict__ x_init,
                                            const float* __restrict__ x_fut,
                                            const float* __restrict__ Wen,
                                            const float* __restrict__ ben,
                                            float* __restrict__ x_gt,
                                            float* __restrict__ z_gt) {
  __shared__ __align__(16) u16 Al[128 * 40];
  __shared__ __align__(16) u16 Bl[256 * 40];
  int t = threadIdx.x;
  long r0 = (long)blockIdx.x * 128;
  int w = t >> 6, l = t & 63, r16 = l & 15, kb = (l >> 4) * 8;
  int wm = w >> 2, wn = w & 3;
  f32x4 acc[4][4];
  #pragma unroll
  for (int i = 0; i < 4; ++i)
    #pragma unroll
    for (int j = 0; j < 4; ++j) acc[i][j] = f32x4{0.f, 0.f, 0.f, 0.f};
  for (int kk = 0; kk < 2; ++kk) {
    int k0 = kk * 32;
    {
      int row = t >> 2, kq = t & 3;
      long gr = r0 + row;
      unsigned bb = (unsigned)gr / 129u;
      unsigned rr = (unsigned)gr - bb * 129u;
      const float* src = (rr == 0) ? (x_init + (size_t)bb * 64)
                                   : (x_fut + ((size_t)bb * 128 + (rr - 1)) * 64);
      float4 v0 = *(const float4*)(src + k0 + kq * 8);
      float4 v1 = *(const float4*)(src + k0 + kq * 8 + 4);
      *(float4*)(&x_gt[gr * 64 + k0 + kq * 8]) = v0;
      *(float4*)(&x_gt[gr * 64 + k0 + kq * 8 + 4]) = v1;
      u16 tmp[8];
      tmp[0] = f2bf(v0.x); tmp[1] = f2bf(v0.y); tmp[2] = f2bf(v0.z); tmp[3] = f2bf(v0.w);
      tmp[4] = f2bf(v1.x); tmp[5] = f2bf(v1.y); tmp[6] = f2bf(v1.z); tmp[7] = f2bf(v1.w);
      *(uint4*)(&Al[row * 40 + kq * 8]) = *(uint4*)(tmp);
    }
    {
      int n = t & 255, kh = (t >> 8) * 16;
      #pragma unroll
      for (int kp = 0; kp < 8; ++kp) {
        int k = k0 + kh + kp * 2;
        float f0 = Wen[(size_t)k * 256 + n];
        float f1 = Wen[(size_t)(k + 1) * 256 + n];
        *(unsigned*)(&Bl[n * 40 + kh + kp * 2]) = ((unsigned)f2bf(f1) << 16) | (unsigned)f2bf(f0);
      }
    }
    __syncthreads();
    bf8 af[4], bf[4];
    #pragma unroll
    for (int mf = 0; mf < 4; ++mf)
      af[mf] = __builtin_bit_cast(bf8, *(const uint4*)(&Al[(wm * 64 + mf * 16 + r16) * 40 + kb]));
    #pragma unroll
    for (int nf = 0; nf < 4; ++nf)
      bf[nf] = __builtin_bit_cast(bf8, *(const uint4*)(&Bl[(wn * 64 + nf * 16 + r16) * 40 + kb]));
    #pragma unroll
    for (int mf = 0; mf < 4; ++mf)
      #pragma unroll
      for (int nf = 0; nf < 4; ++nf)
        acc[mf][nf] = __builtin_amdgcn_mfma_f32_16x16x32_bf16(af[mf], bf[nf], acc[mf][nf], 0, 0, 0);
    __syncthreads();
  }
  #pragma unroll
  for (int nf = 0; nf < 4; ++nf) {
    int c = wn * 64 + nf * 16 + r16;
    float bv = ben[c];
    #pragma unroll
    for (int mf = 0; mf < 4; ++mf) {
      long row0 = r0 + wm * 64 + mf * 16 + (l >> 4) * 4;
      #pragma unroll
      for (int r = 0; r < 4; ++r)
        z_gt[(row0 + r) * 256 + c] = acc[mf][nf][r] + bv;
    }
  }
}

extern "C" void kernel_launch(void* const* d_in, const int* in_sizes, int n_in,
                              void* d_out, int out_size, void* d_ws, size_t ws_size,
                              hipStream_t stream) {
  const float* xh     = (const float*)d_in[0];
  const float* uh     = (const float*)d_in[1];
  const float* x_init = (const float*)d_in[2];
  const float* x_fut  = (const float*)d_in[3];
  const float* u_fut  = (const float*)d_in[4];
  const float* Wc = (const float*)d_in[6];
  const float* bc = (const float*)d_in[7];
  const float* WA = (const float*)d_in[8];
  const float* bA = (const float*)d_in[9];
  const float* WB = (const float*)d_in[10];
  const float* bB = (const float*)d_in[11];
  const float* We = (const float*)d_in[12];
  const float* be = (const float*)d_in[13];
  const float* Wd = (const float*)d_in[14];
  const float* bd = (const float*)d_in[15];

  float* out    = (float*)d_out;
  float* z_traj = out;                 // [256,129,256]
  float* x_traj = out + 8454144;       // [256,129,64]
  float* A_ct   = out + 10567680;      // [256,256,256]
  float* B_mat  = out + 27344896;      // [256,256,32]
  float* z_re   = out + 29442048;      // [256,129,256]
  float* x_gt   = out + 37896192;      // [256,129,64]
  float* z_gt   = out + 40009728;      // [256,129,256]

  // scratch aliased into not-yet-written output regions:
  float* Cf  = z_gt;                   // 33.55MB; consumed by k_seq before k_gt writes z_gt
  float* Wde = x_gt;                   // 256KB;  consumed by k_decenc before k_gt writes x_gt
  float* bde = x_gt + 65536;
  u16*   h_bf = (u16*)d_ws;            // 256KB

  hipLaunchKernelGGL(k_ctxt,   dim3(256),  dim3(512), 0, stream, xh, uh, Wc, bc, h_bf);
  hipLaunchKernelGGL(k_head,   dim3(1024), dim3(256), 0, stream, h_bf, WA, bA, A_ct, 65536);
  hipLaunchKernelGGL(k_head,   dim3(128),  dim3(256), 0, stream, h_bf, WB, bB, B_mat, 8192);
  hipLaunchKernelGGL(k_wde,    dim3(257),  dim3(256), 0, stream, Wd, We, bd, be, Wde, bde);
  hipLaunchKernelGGL(k_cprep,  dim3(256),  dim3(256), 0, stream, B_mat, u_fut, Cf);
  hipLaunchKernelGGL(k_seq,    dim3(256),  dim3(512), 0, stream, A_ct, Cf, x_init, We, be, z_traj);
  hipLaunchKernelGGL(k_decenc, dim3(258),  dim3(512), 0, stream, z_traj, Wd, bd, Wde, bde, x_traj, z_re);
  hipLaunchKernelGGL(k_gt,     dim3(258),  dim3(512), 0, stream, x_init, x_fut, We, be, x_gt, z_gt);
}

// Round 4
// 286.604 us; speedup vs baseline: 1.5101x; 1.0738x over previous
//
#include <hip/hip_runtime.h>

#define DT_C 0.01f

typedef unsigned short u16;
typedef __bf16 bf8 __attribute__((ext_vector_type(8)));
typedef float f32x4 __attribute__((ext_vector_type(4)));

__device__ __forceinline__ u16 f2bf(float f) {
  unsigned u = __float_as_uint(f);
  unsigned r = (u + 0x7FFFu + ((u >> 16) & 1u)) >> 16;
  return (u16)r;
}
__device__ __forceinline__ float bflo(unsigned w) { return __uint_as_float(w << 16); }
__device__ __forceinline__ float bfhi(unsigned w) { return __uint_as_float(w & 0xFFFF0000u); }

// ---- kernel 1: blocks 0..255: context encoder -> h (bf16); blocks 256..512: Wde/bde ----
__global__ __launch_bounds__(512) void k_ctxt2(const float* __restrict__ xh,
                                               const float* __restrict__ uh,
                                               const float* __restrict__ Wc,
                                               const float* __restrict__ bc,
                                               u16* __restrict__ h_bf,
                                               const float* __restrict__ Wd,
                                               const float* __restrict__ We,
                                               const float* __restrict__ bd,
                                               const float* __restrict__ be,
                                               float* __restrict__ Wde,
                                               float* __restrict__ bde) {
  int blk = blockIdx.x, t = threadIdx.x;
  if (blk < 256) {
    __shared__ float m[96];
    int b = blk;
    if (t < 96) {
      float s = 0.f;
      if (t < 64) {
        const float* p = xh + (size_t)b * 2048 + t;
        for (int tt = 0; tt < 32; ++tt) s += p[tt * 64];
      } else {
        const float* p = uh + (size_t)b * 1024 + (t - 64);
        for (int tt = 0; tt < 32; ++tt) s += p[tt * 32];
      }
      m[t] = s * (1.0f / 32.0f);
    }
    __syncthreads();
    float acc = bc[t];
    #pragma unroll 8
    for (int s = 0; s < 96; ++s) acc += m[s] * Wc[s * 512 + t];
    h_bf[b * 512 + t] = f2bf(tanhf(acc));
  } else {
    int i = blk - 256;
    if (t < 256) {
      if (i < 256) {
        float a = 0.f;
        #pragma unroll 8
        for (int s = 0; s < 64; ++s) a += Wd[i * 64 + s] * We[s * 256 + t];
        Wde[i * 256 + t] = a;
      } else {
        float a = be[t];
        #pragma unroll 8
        for (int s = 0; s < 64; ++s) a += bd[s] * We[s * 256 + t];
        bde[t] = a;
      }
    }
  }
}

// ------- kernel 2: head GEMM out[256,N] = h(bf16) @ W(f32 -> bf16) + b -------
__global__ __launch_bounds__(256) void k_head(const u16* __restrict__ hb,
                                              const float* __restrict__ W,
                                              const float* __restrict__ bias,
                                              float* __restrict__ out, int N) {
  __shared__ __align__(16) u16 Al[256 * 40];
  __shared__ __align__(16) u16 Bl[64 * 40];
  int t = threadIdx.x;
  int n0 = blockIdx.x * 64;
  int w = t >> 6, l = t & 63;
  int r16 = l & 15, kb = (l >> 4) * 8;
  f32x4 acc[4][4];
  #pragma unroll
  for (int i = 0; i < 4; ++i)
    #pragma unroll
    for (int j = 0; j < 4; ++j) acc[i][j] = f32x4{0.f, 0.f, 0.f, 0.f};
  for (int kk = 0; kk < 16; ++kk) {
    int k0 = kk * 32;
    {
      int row = t >> 2, kq = t & 3;
      #pragma unroll
      for (int p = 0; p < 4; ++p) {
        int rr = row + 64 * p;
        *(uint4*)(&Al[rr * 40 + kq * 8]) = *(const uint4*)(hb + rr * 512 + k0 + kq * 8);
      }
    }
    {
      int n = t & 63, kp0 = t >> 6;
      #pragma unroll
      for (int r2 = 0; r2 < 4; ++r2) {
        int kp = kp0 * 4 + r2;
        long k = k0 + kp * 2;
        float f0 = W[k * N + n0 + n];
        float f1 = W[(k + 1) * N + n0 + n];
        unsigned pk = ((unsigned)f2bf(f1) << 16) | (unsigned)f2bf(f0);
        *(unsigned*)(&Bl[n * 40 + kp * 2]) = pk;
      }
    }
    __syncthreads();
    bf8 afr[4], bfr[4];
    #pragma unroll
    for (int mf = 0; mf < 4; ++mf)
      afr[mf] = __builtin_bit_cast(bf8, *(const uint4*)(&Al[(w * 64 + mf * 16 + r16) * 40 + kb]));
    #pragma unroll
    for (int nf = 0; nf < 4; ++nf)
      bfr[nf] = __builtin_bit_cast(bf8, *(const uint4*)(&Bl[(nf * 16 + r16) * 40 + kb]));
    #pragma unroll
    for (int mf = 0; mf < 4; ++mf)
      #pragma unroll
      for (int nf = 0; nf < 4; ++nf)
        acc[mf][nf] = __builtin_amdgcn_mfma_f32_16x16x32_bf16(afr[mf], bfr[nf], acc[mf][nf], 0, 0, 0);
    __syncthreads();
  }
  #pragma unroll
  for (int nf = 0; nf < 4; ++nf) {
    int col = n0 + nf * 16 + r16;
    float bv = bias[col];
    #pragma unroll
    for (int mf = 0; mf < 4; ++mf) {
      int row0 = w * 64 + mf * 16 + (l >> 4) * 4;
      #pragma unroll
      for (int r = 0; r < 4; ++r)
        out[(long)(row0 + r) * N + col] = acc[mf][nf][r] + bv;
    }
  }
}

// ---------------- kernel 3: 128-step rollout ----------------
// 512 thr = 8 j-groups x 64 lanes. M^T block (32j x 4i) in f32 regs, loaded
// straight from global (A_ct is L2/L3-warm). c_k = B u_k computed on waves 4-7
// during the reduce phase (double-buffered cbuf), u_fut staged in LDS.
__global__ __launch_bounds__(512) void k_seq(const float* __restrict__ Act,
                                             const float* __restrict__ Bm,
                                             const float* __restrict__ u_fut,
                                             const float* __restrict__ x_init,
                                             const float* __restrict__ We,
                                             const float* __restrict__ be,
                                             float* __restrict__ zt) {
  __shared__ __align__(16) float zx[256];
  __shared__ __align__(16) float part[8][256];
  __shared__ __align__(16) float ul[128 * 32];
  __shared__ __align__(16) float cbuf[2][256];
  int b = blockIdx.x, t = threadIdx.x;
  int jg = t >> 6, li = t & 63, j0 = jg * 32, i0 = li * 4;
  const float* A = Act + (size_t)b * 65536;
  // M^T block into regs: m[jj][r] = DT * A[i0+r][j0+jj]
  float m[32][4];
  #pragma unroll
  for (int r = 0; r < 4; ++r) {
    const float* rp = A + (size_t)(i0 + r) * 256 + j0;
    #pragma unroll
    for (int qq = 0; qq < 8; ++qq) {
      float4 v = *(const float4*)(rp + qq * 4);
      m[qq * 4 + 0][r] = v.x * DT_C;
      m[qq * 4 + 1][r] = v.y * DT_C;
      m[qq * 4 + 2][r] = v.z * DT_C;
      m[qq * 4 + 3][r] = v.w * DT_C;
    }
  }
  // stage u_fut[b] (16 KB)
  {
    const float* ub = u_fut + (size_t)b * 4096;
    *(float4*)(&ul[t * 8])     = *(const float4*)(ub + t * 8);
    *(float4*)(&ul[t * 8 + 4]) = *(const float4*)(ub + t * 8 + 4);
  }
  // B row for c-producer threads
  float br[32];
  if (t >= 256) {
    const float* bp = Bm + (size_t)b * 8192 + (size_t)(t - 256) * 32;
    #pragma unroll
    for (int q = 0; q < 8; ++q) {
      float4 v = *(const float4*)(bp + q * 4);
      br[q * 4] = v.x; br[q * 4 + 1] = v.y; br[q * 4 + 2] = v.z; br[q * 4 + 3] = v.w;
    }
  }
  __syncthreads();   // ul visible
  if (t < 256) {     // z0 = We^T x_init + be
    float z = be[t];
    const float* xi = x_init + b * 64;
    #pragma unroll 8
    for (int s = 0; s < 64; ++s) z += xi[s] * We[s * 256 + t];
    zx[t] = z;
    zt[(size_t)b * 33024 + t] = z;
  } else {           // c_0 into cbuf[0]
    int i = t - 256;
    float c = 0.f;
    #pragma unroll
    for (int q = 0; q < 8; ++q) {
      float4 uv = *(const float4*)(&ul[q * 4]);
      c += br[q * 4] * uv.x + br[q * 4 + 1] * uv.y + br[q * 4 + 2] * uv.z + br[q * 4 + 3] * uv.w;
    }
    cbuf[0][i] = c;
  }
  __syncthreads();
  float* ztb = zt + (size_t)b * 33024;
  for (int k = 0; k < 128; ++k) {
    float a0 = 0.f, a1 = 0.f, a2 = 0.f, a3 = 0.f;
    #pragma unroll
    for (int q = 0; q < 8; ++q) {
      float4 zv = *(const float4*)(&zx[j0 + q * 4]);
      a0 += zv.x * m[4 * q + 0][0]; a1 += zv.x * m[4 * q + 0][1]; a2 += zv.x * m[4 * q + 0][2]; a3 += zv.x * m[4 * q + 0][3];
      a0 += zv.y * m[4 * q + 1][0]; a1 += zv.y * m[4 * q + 1][1]; a2 += zv.y * m[4 * q + 1][2]; a3 += zv.y * m[4 * q + 1][3];
      a0 += zv.z * m[4 * q + 2][0]; a1 += zv.z * m[4 * q + 2][1]; a2 += zv.z * m[4 * q + 2][2]; a3 += zv.z * m[4 * q + 2][3];
      a0 += zv.w * m[4 * q + 3][0]; a1 += zv.w * m[4 * q + 3][1]; a2 += zv.w * m[4 * q + 3][2]; a3 += zv.w * m[4 * q + 3][3];
    }
    *(float4*)(&part[jg][i0]) = make_float4(a0, a1, a2, a3);
    __syncthreads();
    if (t < 256) {
      float nz = zx[t] + cbuf[k & 1][t];
      #pragma unroll
      for (int g = 0; g < 8; ++g) nz += part[g][t];
      zx[t] = nz;
      ztb[(size_t)(k + 1) * 256 + t] = nz;
    } else if (k < 127) {   // produce c_{k+1}
      int i = t - 256;
      float c = 0.f;
      const float* uk = &ul[(k + 1) * 32];
      #pragma unroll
      for (int q = 0; q < 8; ++q) {
        float4 uv = *(const float4*)(uk + q * 4);
        c += br[q * 4] * uv.x + br[q * 4 + 1] * uv.y + br[q * 4 + 2] * uv.z + br[q * 4 + 3] * uv.w;
      }
      cbuf[(k + 1) & 1][i] = c;
    }
    __syncthreads();
  }
}

// ---- kernel 4: fused decode+re-encode: [x_traj | z_re] = z @ [Wd | Wde] + [bd | bde] ----
__global__ __launch_bounds__(512) void k_decenc(const float* __restrict__ z,
                                                const float* __restrict__ Wd,
                                                const float* __restrict__ bd,
                                                const float* __restrict__ Wde,
                                                const float* __restrict__ bde,
                                                float* __restrict__ x_traj,
                                                float* __restrict__ z_re) {
  __shared__ __align__(16) u16 Al[128 * 40];
  __shared__ __align__(16) u16 Bl[320 * 40];
  int t = threadIdx.x;
  long r0 = (long)blockIdx.x * 128;
  int w = t >> 6, l = t & 63, r16 = l & 15, kb = (l >> 4) * 8;
  int wm = w >> 2, wn = w & 3;
  const float* bsrc = (t < 64) ? (Wd + t) : (Wde + (t - 64));
  int bld = (t < 64) ? 64 : 256;
  f32x4 acc[4][5];
  #pragma unroll
  for (int i = 0; i < 4; ++i)
    #pragma unroll
    for (int j = 0; j < 5; ++j) acc[i][j] = f32x4{0.f, 0.f, 0.f, 0.f};
  for (int kk = 0; kk < 8; ++kk) {
    int k0 = kk * 32;
    {
      int row = t >> 2, kq = t & 3;
      const float* zs = z + (r0 + row) * 256 + k0 + kq * 8;
      float4 v0 = *(const float4*)(zs);
      float4 v1 = *(const float4*)(zs + 4);
      u16 tmp[8];
      tmp[0] = f2bf(v0.x); tmp[1] = f2bf(v0.y); tmp[2] = f2bf(v0.z); tmp[3] = f2bf(v0.w);
      tmp[4] = f2bf(v1.x); tmp[5] = f2bf(v1.y); tmp[6] = f2bf(v1.z); tmp[7] = f2bf(v1.w);
      *(uint4*)(&Al[row * 40 + kq * 8]) = *(uint4*)(tmp);
    }
    if (t < 320) {
      #pragma unroll
      for (int kp = 0; kp < 16; ++kp) {
        int k = k0 + kp * 2;
        float f0 = bsrc[(size_t)k * bld];
        float f1 = bsrc[(size_t)(k + 1) * bld];
        *(unsigned*)(&Bl[t * 40 + kp * 2]) = ((unsigned)f2bf(f1) << 16) | (unsigned)f2bf(f0);
      }
    }
    __syncthreads();
    bf8 af[4], bf[5];
    #pragma unroll
    for (int mf = 0; mf < 4; ++mf)
      af[mf] = __builtin_bit_cast(bf8, *(const uint4*)(&Al[(wm * 64 + mf * 16 + r16) * 40 + kb]));
    #pragma unroll
    for (int nf = 0; nf < 5; ++nf)
      bf[nf] = __builtin_bit_cast(bf8, *(const uint4*)(&Bl[(wn * 80 + nf * 16 + r16) * 40 + kb]));
    #pragma unroll
    for (int mf = 0; mf < 4; ++mf)
      #pragma unroll
      for (int nf = 0; nf < 5; ++nf)
        acc[mf][nf] = __builtin_amdgcn_mfma_f32_16x16x32_bf16(af[mf], bf[nf], acc[mf][nf], 0, 0, 0);
    __syncthreads();
  }
  #pragma unroll
  for (int nf = 0; nf < 5; ++nf) {
    int c = wn * 80 + nf * 16 + r16;
    float bv = (c < 64) ? bd[c] : bde[c - 64];
    #pragma unroll
    for (int mf = 0; mf < 4; ++mf) {
      long row0 = r0 + wm * 64 + mf * 16 + (l >> 4) * 4;
      #pragma unroll
      for (int r = 0; r < 4; ++r) {
        float val = acc[mf][nf][r] + bv;
        if (c < 64) x_traj[(row0 + r) * 64 + c] = val;
        else        z_re[(row0 + r) * 256 + (c - 64)] = val;
      }
    }
  }
}

// ---- kernel 5: assemble x_gt, z_gt = x_gt @ We + be. BM=128, N=256, K=64 ----
__global__ __launch_bounds__(512) void k_gt(const float* __restrict__ x_init,
                                            const float* __restrict__ x_fut,
                                            const float* __restrict__ Wen,
                                            const float* __restrict__ ben,
                                            float* __restrict__ x_gt,
                                            float* __restrict__ z_gt) {
  __shared__ __align__(16) u16 Al[128 * 40];
  __shared__ __align__(16) u16 Bl[256 * 40];
  int t = threadIdx.x;
  long r0 = (long)blockIdx.x * 128;
  int w = t >> 6, l = t & 63, r16 = l & 15, kb = (l >> 4) * 8;
  int wm = w >> 2, wn = w & 3;
  f32x4 acc[4][4];
  #pragma unroll
  for (int i = 0; i < 4; ++i)
    #pragma unroll
    for (int j = 0; j < 4; ++j) acc[i][j] = f32x4{0.f, 0.f, 0.f, 0.f};
  for (int kk = 0; kk < 2; ++kk) {
    int k0 = kk * 32;
    {
      int row = t >> 2, kq = t & 3;
      long gr = r0 + row;
      unsigned bb = (unsigned)gr / 129u;
      unsigned rr = (unsigned)gr - bb * 129u;
      const float* src = (rr == 0) ? (x_init + (size_t)bb * 64)
                                   : (x_fut + ((size_t)bb * 128 + (rr - 1)) * 64);
      float4 v0 = *(const float4*)(src + k0 + kq * 8);
      float4 v1 = *(const float4*)(src + k0 + kq * 8 + 4);
      *(float4*)(&x_gt[gr * 64 + k0 + kq * 8]) = v0;
      *(float4*)(&x_gt[gr * 64 + k0 + kq * 8 + 4]) = v1;
      u16 tmp[8];
      tmp[0] = f2bf(v0.x); tmp[1] = f2bf(v0.y); tmp[2] = f2bf(v0.z); tmp[3] = f2bf(v0.w);
      tmp[4] = f2bf(v1.x); tmp[5] = f2bf(v1.y); tmp[6] = f2bf(v1.z); tmp[7] = f2bf(v1.w);
      *(uint4*)(&Al[row * 40 + kq * 8]) = *(uint4*)(tmp);
    }
    {
      int n = t & 255, kh = (t >> 8) * 16;
      #pragma unroll
      for (int kp = 0; kp < 8; ++kp) {
        int k = k0 + kh + kp * 2;
        float f0 = Wen[(size_t)k * 256 + n];
        float f1 = Wen[(size_t)(k + 1) * 256 + n];
        *(unsigned*)(&Bl[n * 40 + kh + kp * 2]) = ((unsigned)f2bf(f1) << 16) | (unsigned)f2bf(f0);
      }
    }
    __syncthreads();
    bf8 af[4], bf[4];
    #pragma unroll
    for (int mf = 0; mf < 4; ++mf)
      af[mf] = __builtin_bit_cast(bf8, *(const uint4*)(&Al[(wm * 64 + mf * 16 + r16) * 40 + kb]));
    #pragma unroll
    for (int nf = 0; nf < 4; ++nf)
      bf[nf] = __builtin_bit_cast(bf8, *(const uint4*)(&Bl[(wn * 64 + nf * 16 + r16) * 40 + kb]));
    #pragma unroll
    for (int mf = 0; mf < 4; ++mf)
      #pragma unroll
      for (int nf = 0; nf < 4; ++nf)
        acc[mf][nf] = __builtin_amdgcn_mfma_f32_16x16x32_bf16(af[mf], bf[nf], acc[mf][nf], 0, 0, 0);
    __syncthreads();
  }
  #pragma unroll
  for (int nf = 0; nf < 4; ++nf) {
    int c = wn * 64 + nf * 16 + r16;
    float bv = ben[c];
    #pragma unroll
    for (int mf = 0; mf < 4; ++mf) {
      long row0 = r0 + wm * 64 + mf * 16 + (l >> 4) * 4;
      #pragma unroll
      for (int r = 0; r < 4; ++r)
        z_gt[(row0 + r) * 256 + c] = acc[mf][nf][r] + bv;
    }
  }
}

extern "C" void kernel_launch(void* const* d_in, const int* in_sizes, int n_in,
                              void* d_out, int out_size, void* d_ws, size_t ws_size,
                              hipStream_t stream) {
  const float* xh     = (const float*)d_in[0];
  const float* uh     = (const float*)d_in[1];
  const float* x_init = (const float*)d_in[2];
  const float* x_fut  = (const float*)d_in[3];
  const float* u_fut  = (const float*)d_in[4];
  const float* Wc = (const float*)d_in[6];
  const float* bc = (const float*)d_in[7];
  const float* WA = (const float*)d_in[8];
  const float* bA = (const float*)d_in[9];
  const float* WB = (const float*)d_in[10];
  const float* bB = (const float*)d_in[11];
  const float* We = (const float*)d_in[12];
  const float* be = (const float*)d_in[13];
  const float* Wd = (const float*)d_in[14];
  const float* bd = (const float*)d_in[15];

  float* out    = (float*)d_out;
  float* z_traj = out;                 // [256,129,256]
  float* x_traj = out + 8454144;       // [256,129,64]
  float* A_ct   = out + 10567680;      // [256,256,256]
  float* B_mat  = out + 27344896;      // [256,256,32]
  float* z_re   = out + 29442048;      // [256,129,256]
  float* x_gt   = out + 37896192;      // [256,129,64]
  float* z_gt   = out + 40009728;      // [256,129,256]

  // scratch aliased into not-yet-written output regions:
  float* Wde = x_gt;                   // 256KB; consumed by k_decenc before k_gt writes x_gt
  float* bde = x_gt + 65536;
  u16*   h_bf = (u16*)d_ws;            // 256KB

  hipLaunchKernelGGL(k_ctxt2,  dim3(513),  dim3(512), 0, stream, xh, uh, Wc, bc, h_bf,
                     Wd, We, bd, be, Wde, bde);
  hipLaunchKernelGGL(k_head,   dim3(1024), dim3(256), 0, stream, h_bf, WA, bA, A_ct, 65536);
  hipLaunchKernelGGL(k_head,   dim3(128),  dim3(256), 0, stream, h_bf, WB, bB, B_mat, 8192);
  hipLaunchKernelGGL(k_seq,    dim3(256),  dim3(512), 0, stream, A_ct, B_mat, u_fut, x_init, We, be, z_traj);
  hipLaunchKernelGGL(k_decenc, dim3(258),  dim3(512), 0, stream, z_traj, Wd, bd, Wde, bde, x_traj, z_re);
  hipLaunchKernelGGL(k_gt,     dim3(258),  dim3(512), 0, stream, x_init, x_fut, We, be, x_gt, z_gt);
}

// Round 5
// 235.079 us; speedup vs baseline: 1.8411x; 1.2192x over previous
//
#include <hip/hip_runtime.h>

#define DT_C 0.01f

typedef unsigned short u16;
typedef __bf16 bf8 __attribute__((ext_vector_type(8)));
typedef float f32x4 __attribute__((ext_vector_type(4)));

__device__ __forceinline__ u16 f2bf(float f) {
  unsigned u = __float_as_uint(f);
  unsigned r = (u + 0x7FFFu + ((u >> 16) & 1u)) >> 16;
  return (u16)r;
}
__device__ __forceinline__ float bflo(unsigned w) { return __uint_as_float(w << 16); }
__device__ __forceinline__ float bfhi(unsigned w) { return __uint_as_float(w & 0xFFFF0000u); }

// LDS-only barrier: drains lgkmcnt (cross-wave LDS visibility) but NOT vmcnt,
// so in-flight global stores don't serialize the scan loop.
__device__ __forceinline__ void wg_barrier() {
  asm volatile("s_waitcnt lgkmcnt(0)" ::: "memory");
  __builtin_amdgcn_s_barrier();
}

// ---------------- kernel 1: context encoder -> h (bf16) ----------------
__global__ __launch_bounds__(512) void k_ctxt(const float* __restrict__ xh,
                                              const float* __restrict__ uh,
                                              const float* __restrict__ Wc,
                                              const float* __restrict__ bc,
                                              u16* __restrict__ h_bf) {
  __shared__ float m[96];
  int b = blockIdx.x, t = threadIdx.x;
  if (t < 96) {
    float s = 0.f;
    if (t < 64) {
      const float* p = xh + (size_t)b * 2048 + t;
      for (int tt = 0; tt < 32; ++tt) s += p[tt * 64];
    } else {
      const float* p = uh + (size_t)b * 1024 + (t - 64);
      for (int tt = 0; tt < 32; ++tt) s += p[tt * 32];
    }
    m[t] = s * (1.0f / 32.0f);
  }
  __syncthreads();
  float acc = bc[t];
  #pragma unroll 8
  for (int s = 0; s < 96; ++s) acc += m[s] * Wc[s * 512 + t];
  h_bf[b * 512 + t] = f2bf(tanhf(acc));
}

// ------- kernel 2: merged head GEMMs. blocks <1024: A_ct (N=65536); else B_mat (N=8192) -------
__global__ __launch_bounds__(256) void k_heads(const u16* __restrict__ hb,
                                               const float* __restrict__ WA,
                                               const float* __restrict__ bA,
                                               const float* __restrict__ WB,
                                               const float* __restrict__ bB,
                                               float* __restrict__ A_ct,
                                               float* __restrict__ B_mat) {
  __shared__ __align__(16) u16 Al[256 * 40];
  __shared__ __align__(16) u16 Bl[64 * 40];
  int t = threadIdx.x;
  const float* W; const float* bias; float* out; int N; int n0;
  if (blockIdx.x < 1024) { W = WA; bias = bA; out = A_ct; N = 65536; n0 = blockIdx.x * 64; }
  else                   { W = WB; bias = bB; out = B_mat; N = 8192; n0 = (blockIdx.x - 1024) * 64; }
  int w = t >> 6, l = t & 63;
  int r16 = l & 15, kb = (l >> 4) * 8;
  f32x4 acc[4][4];
  #pragma unroll
  for (int i = 0; i < 4; ++i)
    #pragma unroll
    for (int j = 0; j < 4; ++j) acc[i][j] = f32x4{0.f, 0.f, 0.f, 0.f};
  for (int kk = 0; kk < 16; ++kk) {
    int k0 = kk * 32;
    {
      int row = t >> 2, kq = t & 3;
      #pragma unroll
      for (int p = 0; p < 4; ++p) {
        int rr = row + 64 * p;
        *(uint4*)(&Al[rr * 40 + kq * 8]) = *(const uint4*)(hb + rr * 512 + k0 + kq * 8);
      }
    }
    {
      int n = t & 63, kp0 = t >> 6;
      #pragma unroll
      for (int r2 = 0; r2 < 4; ++r2) {
        int kp = kp0 * 4 + r2;
        long k = k0 + kp * 2;
        float f0 = W[k * N + n0 + n];
        float f1 = W[(k + 1) * N + n0 + n];
        unsigned pk = ((unsigned)f2bf(f1) << 16) | (unsigned)f2bf(f0);
        *(unsigned*)(&Bl[n * 40 + kp * 2]) = pk;
      }
    }
    __syncthreads();
    bf8 afr[4], bfr[4];
    #pragma unroll
    for (int mf = 0; mf < 4; ++mf)
      afr[mf] = __builtin_bit_cast(bf8, *(const uint4*)(&Al[(w * 64 + mf * 16 + r16) * 40 + kb]));
    #pragma unroll
    for (int nf = 0; nf < 4; ++nf)
      bfr[nf] = __builtin_bit_cast(bf8, *(const uint4*)(&Bl[(nf * 16 + r16) * 40 + kb]));
    #pragma unroll
    for (int mf = 0; mf < 4; ++mf)
      #pragma unroll
      for (int nf = 0; nf < 4; ++nf)
        acc[mf][nf] = __builtin_amdgcn_mfma_f32_16x16x32_bf16(afr[mf], bfr[nf], acc[mf][nf], 0, 0, 0);
    __syncthreads();
  }
  #pragma unroll
  for (int nf = 0; nf < 4; ++nf) {
    int col = n0 + nf * 16 + r16;
    float bv = bias[col];
    #pragma unroll
    for (int mf = 0; mf < 4; ++mf) {
      int row0 = w * 64 + mf * 16 + (l >> 4) * 4;
      #pragma unroll
      for (int r = 0; r < 4; ++r)
        out[(long)(row0 + r) * N + col] = acc[mf][nf][r] + bv;
    }
  }
}

// ---- kernel 3: blocks 0..255: 128-step rollout; blocks 256..513: x_gt/z_gt GEMM ----
__global__ __launch_bounds__(512) void k_seqgt(const float* __restrict__ Act,
                                               const float* __restrict__ Bm,
                                               const float* __restrict__ u_fut,
                                               const float* __restrict__ x_init,
                                               const float* __restrict__ x_fut,
                                               const float* __restrict__ We,
                                               const float* __restrict__ be,
                                               float* __restrict__ zt,
                                               float* __restrict__ x_gt,
                                               float* __restrict__ z_gt) {
  extern __shared__ __align__(16) char smem[];
  int t = threadIdx.x;
  if (blockIdx.x < 256) {
    // ---------------- scan branch ----------------
    float* ul   = (float*)(smem);            // [128*32] u_fut staged
    float* part = (float*)(smem + 16384);    // [8][256]
    float* cbuf = (float*)(smem + 24576);    // [2][256]
    u16*  zxb   = (u16*)(smem + 26624);      // [256] z broadcast (bf16)
    int b = blockIdx.x;
    int jg = t >> 6, li = t & 63, j0 = jg * 32, i0 = li * 4;
    const float* A = Act + (size_t)b * 65536;
    // M^T block into regs: m[jj][r] = DT * A[i0+r][j0+jj]
    float m[32][4];
    #pragma unroll
    for (int r = 0; r < 4; ++r) {
      const float* rp = A + (size_t)(i0 + r) * 256 + j0;
      #pragma unroll
      for (int qq = 0; qq < 8; ++qq) {
        float4 v = *(const float4*)(rp + qq * 4);
        m[qq * 4 + 0][r] = v.x * DT_C;
        m[qq * 4 + 1][r] = v.y * DT_C;
        m[qq * 4 + 2][r] = v.z * DT_C;
        m[qq * 4 + 3][r] = v.w * DT_C;
      }
    }
    {
      const float* ub = u_fut + (size_t)b * 4096;
      *(float4*)(&ul[t * 8])     = *(const float4*)(ub + t * 8);
      *(float4*)(&ul[t * 8 + 4]) = *(const float4*)(ub + t * 8 + 4);
    }
    float br[32];
    if (t >= 256) {
      const float* bp = Bm + (size_t)b * 8192 + (size_t)(t - 256) * 32;
      #pragma unroll
      for (int q = 0; q < 8; ++q) {
        float4 v = *(const float4*)(bp + q * 4);
        br[q * 4] = v.x; br[q * 4 + 1] = v.y; br[q * 4 + 2] = v.z; br[q * 4 + 3] = v.w;
      }
    }
    __syncthreads();
    float zreg = 0.f;
    if (t < 256) {
      float z = be[t];
      const float* xi = x_init + b * 64;
      #pragma unroll 8
      for (int s = 0; s < 64; ++s) z += xi[s] * We[s * 256 + t];
      zreg = z;
      zxb[t] = f2bf(z);
      zt[(size_t)b * 33024 + t] = z;
    } else {
      int i = t - 256;
      float c = 0.f;
      #pragma unroll
      for (int q = 0; q < 8; ++q) {
        float4 uv = *(const float4*)(&ul[q * 4]);
        c += br[q * 4] * uv.x + br[q * 4 + 1] * uv.y + br[q * 4 + 2] * uv.z + br[q * 4 + 3] * uv.w;
      }
      cbuf[i] = c;
    }
    __syncthreads();
    float* ztb = zt + (size_t)b * 33024;
    for (int k = 0; k < 128; ++k) {
      float a0 = 0.f, a1 = 0.f, a2 = 0.f, a3 = 0.f;
      #pragma unroll
      for (int qq = 0; qq < 4; ++qq) {
        uint4 wz = *(const uint4*)(&zxb[j0 + qq * 8]);
        unsigned ww[4] = {wz.x, wz.y, wz.z, wz.w};
        #pragma unroll
        for (int p = 0; p < 4; ++p) {
          int jj = qq * 8 + p * 2;
          float zl = bflo(ww[p]), zh = bfhi(ww[p]);
          a0 += zl * m[jj][0];     a1 += zl * m[jj][1];
          a2 += zl * m[jj][2];     a3 += zl * m[jj][3];
          a0 += zh * m[jj + 1][0]; a1 += zh * m[jj + 1][1];
          a2 += zh * m[jj + 1][2]; a3 += zh * m[jj + 1][3];
        }
      }
      *(float4*)(&part[jg * 256 + i0]) = make_float4(a0, a1, a2, a3);
      wg_barrier();
      if (t < 256) {
        float nz = zreg + cbuf[(k & 1) * 256 + t];
        #pragma unroll
        for (int g = 0; g < 8; ++g) nz += part[g * 256 + t];
        zreg = nz;
        zxb[t] = f2bf(nz);
        ztb[(size_t)(k + 1) * 256 + t] = nz;
      } else if (k < 127) {
        int i = t - 256;
        float c = 0.f;
        const float* uk = &ul[(k + 1) * 32];
        #pragma unroll
        for (int q = 0; q < 8; ++q) {
          float4 uv = *(const float4*)(uk + q * 4);
          c += br[q * 4] * uv.x + br[q * 4 + 1] * uv.y + br[q * 4 + 2] * uv.z + br[q * 4 + 3] * uv.w;
        }
        cbuf[((k + 1) & 1) * 256 + i] = c;
      }
      wg_barrier();
    }
  } else {
    // ---------------- gt branch: assemble x_gt, z_gt = x_gt @ We + be ----------------
    u16* Al = (u16*)(smem);          // [128*40]
    u16* Bl = (u16*)(smem + 10240);  // [256*40]
    long r0 = (long)(blockIdx.x - 256) * 128;
    int w = t >> 6, l = t & 63, r16 = l & 15, kb = (l >> 4) * 8;
    int wm = w >> 2, wn = w & 3;
    f32x4 acc[4][4];
    #pragma unroll
    for (int i = 0; i < 4; ++i)
      #pragma unroll
      for (int j = 0; j < 4; ++j) acc[i][j] = f32x4{0.f, 0.f, 0.f, 0.f};
    for (int kk = 0; kk < 2; ++kk) {
      int k0 = kk * 32;
      {
        int row = t >> 2, kq = t & 3;
        long gr = r0 + row;
        unsigned bb = (unsigned)gr / 129u;
        unsigned rr = (unsigned)gr - bb * 129u;
        const float* src = (rr == 0) ? (x_init + (size_t)bb * 64)
                                     : (x_fut + ((size_t)bb * 128 + (rr - 1)) * 64);
        float4 v0 = *(const float4*)(src + k0 + kq * 8);
        float4 v1 = *(const float4*)(src + k0 + kq * 8 + 4);
        *(float4*)(&x_gt[gr * 64 + k0 + kq * 8]) = v0;
        *(float4*)(&x_gt[gr * 64 + k0 + kq * 8 + 4]) = v1;
        u16 tmp[8];
        tmp[0] = f2bf(v0.x); tmp[1] = f2bf(v0.y); tmp[2] = f2bf(v0.z); tmp[3] = f2bf(v0.w);
        tmp[4] = f2bf(v1.x); tmp[5] = f2bf(v1.y); tmp[6] = f2bf(v1.z); tmp[7] = f2bf(v1.w);
        *(uint4*)(&Al[row * 40 + kq * 8]) = *(uint4*)(tmp);
      }
      {
        int n = t & 255, kh = (t >> 8) * 16;
        #pragma unroll
        for (int kp = 0; kp < 8; ++kp) {
          int k = k0 + kh + kp * 2;
          float f0 = We[(size_t)k * 256 + n];
          float f1 = We[(size_t)(k + 1) * 256 + n];
          *(unsigned*)(&Bl[n * 40 + kh + kp * 2]) = ((unsigned)f2bf(f1) << 16) | (unsigned)f2bf(f0);
        }
      }
      __syncthreads();
      bf8 af[4], bfv[4];
      #pragma unroll
      for (int mf = 0; mf < 4; ++mf)
        af[mf] = __builtin_bit_cast(bf8, *(const uint4*)(&Al[(wm * 64 + mf * 16 + r16) * 40 + kb]));
      #pragma unroll
      for (int nf = 0; nf < 4; ++nf)
        bfv[nf] = __builtin_bit_cast(bf8, *(const uint4*)(&Bl[(wn * 64 + nf * 16 + r16) * 40 + kb]));
      #pragma unroll
      for (int mf = 0; mf < 4; ++mf)
        #pragma unroll
        for (int nf = 0; nf < 4; ++nf)
          acc[mf][nf] = __builtin_amdgcn_mfma_f32_16x16x32_bf16(af[mf], bfv[nf], acc[mf][nf], 0, 0, 0);
      __syncthreads();
    }
    #pragma unroll
    for (int nf = 0; nf < 4; ++nf) {
      int c = wn * 64 + nf * 16 + r16;
      float bv = be[c];
      #pragma unroll
      for (int mf = 0; mf < 4; ++mf) {
        long row0 = r0 + wm * 64 + mf * 16 + (l >> 4) * 4;
        #pragma unroll
        for (int r = 0; r < 4; ++r)
          z_gt[(row0 + r) * 256 + c] = acc[mf][nf][r] + bv;
      }
    }
  }
}

// ---- kernel 4: x_traj = z@Wd+bd; z_re = bf16(x_traj)@We+be (two-phase, no Wde) ----
__global__ __launch_bounds__(512) void k_decenc2(const float* __restrict__ z,
                                                 const float* __restrict__ Wd,
                                                 const float* __restrict__ bd,
                                                 const float* __restrict__ We,
                                                 const float* __restrict__ be,
                                                 float* __restrict__ x_traj,
                                                 float* __restrict__ z_re) {
  __shared__ __align__(16) char sm[55296];
  u16* Al  = (u16*)(sm);           // [128*40] phase1 (dead in phase2)
  u16* Bl  = (u16*)(sm + 10240);   // [64*40]  phase1 (dead in phase2)
  u16* Xl  = (u16*)(sm);           // [128*72] phase2 x-tile (overlays Al+Bl)
  u16* Bl2 = (u16*)(sm + 18432);   // [256*72] We staged once
  int t = threadIdx.x;
  long r0 = (long)blockIdx.x * 128;
  int w = t >> 6, l = t & 63, r16 = l & 15, kb = (l >> 4) * 8;
  int wm = w >> 2, wn = w & 3;
  // stage We -> Bl2[n][k] (256 x 64), once
  {
    int n = t & 255, kh = (t >> 8) * 32;
    #pragma unroll
    for (int kp = 0; kp < 16; ++kp) {
      int k = kh + kp * 2;
      float f0 = We[(size_t)k * 256 + n];
      float f1 = We[(size_t)(k + 1) * 256 + n];
      *(unsigned*)(&Bl2[n * 72 + kh + kp * 2]) = ((unsigned)f2bf(f1) << 16) | (unsigned)f2bf(f0);
    }
  }
  // ---- phase 1: x = z @ Wd + bd  (M=128, N=64, K=256) ----
  f32x4 acc1[4];
  #pragma unroll
  for (int i = 0; i < 4; ++i) acc1[i] = f32x4{0.f, 0.f, 0.f, 0.f};
  for (int kk = 0; kk < 8; ++kk) {
    int k0 = kk * 32;
    {
      int row = t >> 2, kq = t & 3;
      const float* zs = z + (r0 + row) * 256 + k0 + kq * 8;
      float4 v0 = *(const float4*)(zs);
      float4 v1 = *(const float4*)(zs + 4);
      u16 tmp[8];
      tmp[0] = f2bf(v0.x); tmp[1] = f2bf(v0.y); tmp[2] = f2bf(v0.z); tmp[3] = f2bf(v0.w);
      tmp[4] = f2bf(v1.x); tmp[5] = f2bf(v1.y); tmp[6] = f2bf(v1.z); tmp[7] = f2bf(v1.w);
      *(uint4*)(&Al[row * 40 + kq * 8]) = *(uint4*)(tmp);
    }
    {
      int c = t & 63, kp0 = (t >> 6) * 2;
      #pragma unroll
      for (int r2 = 0; r2 < 2; ++r2) {
        int kp = kp0 + r2;
        int k = k0 + kp * 2;
        float f0 = Wd[(size_t)k * 64 + c];
        float f1 = Wd[(size_t)(k + 1) * 64 + c];
        *(unsigned*)(&Bl[c * 40 + kp * 2]) = ((unsigned)f2bf(f1) << 16) | (unsigned)f2bf(f0);
      }
    }
    __syncthreads();
    bf8 af[4];
    #pragma unroll
    for (int mf = 0; mf < 4; ++mf)
      af[mf] = __builtin_bit_cast(bf8, *(const uint4*)(&Al[(wm * 64 + mf * 16 + r16) * 40 + kb]));
    bf8 bf1 = __builtin_bit_cast(bf8, *(const uint4*)(&Bl[(wn * 16 + r16) * 40 + kb]));
    #pragma unroll
    for (int mf = 0; mf < 4; ++mf)
      acc1[mf] = __builtin_amdgcn_mfma_f32_16x16x32_bf16(af[mf], bf1, acc1[mf], 0, 0, 0);
    __syncthreads();
  }
  // epilogue 1: write x_traj + stage x-tile (bf16) into Xl
  {
    int c = wn * 16 + r16;
    float bv = bd[c];
    #pragma unroll
    for (int mf = 0; mf < 4; ++mf) {
      int rowb = wm * 64 + mf * 16 + (l >> 4) * 4;
      #pragma unroll
      for (int r = 0; r < 4; ++r) {
        float val = acc1[mf][r] + bv;
        x_traj[(r0 + rowb + r) * 64 + c] = val;
        Xl[(rowb + r) * 72 + c] = f2bf(val);
      }
    }
  }
  __syncthreads();
  // ---- phase 2: z_re = x @ We + be  (M=128, N=256, K=64) ----
  f32x4 acc2[4][4];
  #pragma unroll
  for (int i = 0; i < 4; ++i)
    #pragma unroll
    for (int j = 0; j < 4; ++j) acc2[i][j] = f32x4{0.f, 0.f, 0.f, 0.f};
  #pragma unroll
  for (int kk = 0; kk < 2; ++kk) {
    int k0 = kk * 32;
    bf8 af[4], bfv[4];
    #pragma unroll
    for (int mf = 0; mf < 4; ++mf)
      af[mf] = __builtin_bit_cast(bf8, *(const uint4*)(&Xl[(wm * 64 + mf * 16 + r16) * 72 + k0 + kb]));
    #pragma unroll
    for (int nf = 0; nf < 4; ++nf)
      bfv[nf] = __builtin_bit_cast(bf8, *(const uint4*)(&Bl2[(wn * 64 + nf * 16 + r16) * 72 + k0 + kb]));
    #pragma unroll
    for (int mf = 0; mf < 4; ++mf)
      #pragma unroll
      for (int nf = 0; nf < 4; ++nf)
        acc2[mf][nf] = __builtin_amdgcn_mfma_f32_16x16x32_bf16(af[mf], bfv[nf], acc2[mf][nf], 0, 0, 0);
  }
  #pragma unroll
  for (int nf = 0; nf < 4; ++nf) {
    int c = wn * 64 + nf * 16 + r16;
    float bv = be[c];
    #pragma unroll
    for (int mf = 0; mf < 4; ++mf) {
      long row0 = r0 + wm * 64 + mf * 16 + (l >> 4) * 4;
      #pragma unroll
      for (int r = 0; r < 4; ++r)
        z_re[(row0 + r) * 256 + c] = acc2[mf][nf][r] + bv;
    }
  }
}

extern "C" void kernel_launch(void* const* d_in, const int* in_sizes, int n_in,
                              void* d_out, int out_size, void* d_ws, size_t ws_size,
                              hipStream_t stream) {
  const float* xh     = (const float*)d_in[0];
  const float* uh     = (const float*)d_in[1];
  const float* x_init = (const float*)d_in[2];
  const float* x_fut  = (const float*)d_in[3];
  const float* u_fut  = (const float*)d_in[4];
  const float* Wc = (const float*)d_in[6];
  const float* bc = (const float*)d_in[7];
  const float* WA = (const float*)d_in[8];
  const float* bA = (const float*)d_in[9];
  const float* WB = (const float*)d_in[10];
  const float* bB = (const float*)d_in[11];
  const float* We = (const float*)d_in[12];
  const float* be = (const float*)d_in[13];
  const float* Wd = (const float*)d_in[14];
  const float* bd = (const float*)d_in[15];

  float* out    = (float*)d_out;
  float* z_traj = out;                 // [256,129,256]
  float* x_traj = out + 8454144;       // [256,129,64]
  float* A_ct   = out + 10567680;      // [256,256,256]
  float* B_mat  = out + 27344896;      // [256,256,32]
  float* z_re   = out + 29442048;      // [256,129,256]
  float* x_gt   = out + 37896192;      // [256,129,64]
  float* z_gt   = out + 40009728;      // [256,129,256]

  u16* h_bf = (u16*)d_ws;              // 256KB

  hipLaunchKernelGGL(k_ctxt,    dim3(256),  dim3(512), 0,     stream, xh, uh, Wc, bc, h_bf);
  hipLaunchKernelGGL(k_heads,   dim3(1152), dim3(256), 0,     stream, h_bf, WA, bA, WB, bB, A_ct, B_mat);
  hipLaunchKernelGGL(k_seqgt,   dim3(514),  dim3(512), 30720, stream, A_ct, B_mat, u_fut, x_init, x_fut,
                     We, be, z_traj, x_gt, z_gt);
  hipLaunchKernelGGL(k_decenc2, dim3(258),  dim3(512), 0,     stream, z_traj, Wd, bd, We, be, x_traj, z_re);
}

// Round 7
// 230.702 us; speedup vs baseline: 1.8761x; 1.0190x over previous
//
#include <hip/hip_runtime.h>

#define DT_C 0.01f

typedef unsigned short u16;
typedef __bf16 bf8 __attribute__((ext_vector_type(8)));
typedef __fp16 h2 __attribute__((ext_vector_type(2)));
typedef float f32x4 __attribute__((ext_vector_type(4)));

__device__ __forceinline__ u16 f2bf(float f) {
  unsigned u = __float_as_uint(f);
  unsigned r = (u + 0x7FFFu + ((u >> 16) & 1u)) >> 16;
  return (u16)r;
}
__device__ __forceinline__ float bflo(unsigned w) { return __uint_as_float(w << 16); }
__device__ __forceinline__ float bfhi(unsigned w) { return __uint_as_float(w & 0xFFFF0000u); }
__device__ __forceinline__ h2 pkh(float a, float b) { return __builtin_amdgcn_cvt_pkrtz(a, b); }
__device__ __forceinline__ h2 ash2(unsigned v) { return __builtin_bit_cast(h2, v); }

// LDS-only barrier: drains lgkmcnt but NOT vmcnt, so in-flight global stores
// don't serialize the scan loop.
__device__ __forceinline__ void wg_barrier() {
  asm volatile("s_waitcnt lgkmcnt(0)" ::: "memory");
  __builtin_amdgcn_s_barrier();
}

// ---------------- kernel 1: context encoder -> h (bf16) ----------------
__global__ __launch_bounds__(512) void k_ctxt(const float* __restrict__ xh,
                                              const float* __restrict__ uh,
                                              const float* __restrict__ Wc,
                                              const float* __restrict__ bc,
                                              u16* __restrict__ h_bf) {
  __shared__ float m[96];
  int b = blockIdx.x, t = threadIdx.x;
  if (t < 96) {
    float s = 0.f;
    if (t < 64) {
      const float* p = xh + (size_t)b * 2048 + t;
      for (int tt = 0; tt < 32; ++tt) s += p[tt * 64];
    } else {
      const float* p = uh + (size_t)b * 1024 + (t - 64);
      for (int tt = 0; tt < 32; ++tt) s += p[tt * 32];
    }
    m[t] = s * (1.0f / 32.0f);
  }
  __syncthreads();
  float acc = bc[t];
  #pragma unroll 8
  for (int s = 0; s < 96; ++s) acc += m[s] * Wc[s * 512 + t];
  h_bf[b * 512 + t] = f2bf(tanhf(acc));
}

// ------- kernel 2: merged head GEMMs. blocks <1024: A_ct (N=65536); else B_mat (N=8192) -------
__global__ __launch_bounds__(256) void k_heads(const u16* __restrict__ hb,
                                               const float* __restrict__ WA,
                                               const float* __restrict__ bA,
                                               const float* __restrict__ WB,
                                               const float* __restrict__ bB,
                                               float* __restrict__ A_ct,
                                               float* __restrict__ B_mat) {
  __shared__ __align__(16) u16 Al[256 * 40];
  __shared__ __align__(16) u16 Bl[64 * 40];
  int t = threadIdx.x;
  const float* W; const float* bias; float* out; int N; int n0;
  if (blockIdx.x < 1024) { W = WA; bias = bA; out = A_ct; N = 65536; n0 = blockIdx.x * 64; }
  else                   { W = WB; bias = bB; out = B_mat; N = 8192; n0 = (blockIdx.x - 1024) * 64; }
  int w = t >> 6, l = t & 63;
  int r16 = l & 15, kb = (l >> 4) * 8;
  f32x4 acc[4][4];
  #pragma unroll
  for (int i = 0; i < 4; ++i)
    #pragma unroll
    for (int j = 0; j < 4; ++j) acc[i][j] = f32x4{0.f, 0.f, 0.f, 0.f};
  for (int kk = 0; kk < 16; ++kk) {
    int k0 = kk * 32;
    {
      int row = t >> 2, kq = t & 3;
      #pragma unroll
      for (int p = 0; p < 4; ++p) {
        int rr = row + 64 * p;
        *(uint4*)(&Al[rr * 40 + kq * 8]) = *(const uint4*)(hb + rr * 512 + k0 + kq * 8);
      }
    }
    {
      int n = t & 63, kp0 = t >> 6;
      #pragma unroll
      for (int r2 = 0; r2 < 4; ++r2) {
        int kp = kp0 * 4 + r2;
        long k = k0 + kp * 2;
        float f0 = W[k * N + n0 + n];
        float f1 = W[(k + 1) * N + n0 + n];
        unsigned pk = ((unsigned)f2bf(f1) << 16) | (unsigned)f2bf(f0);
        *(unsigned*)(&Bl[n * 40 + kp * 2]) = pk;
      }
    }
    __syncthreads();
    bf8 afr[4], bfr[4];
    #pragma unroll
    for (int mf = 0; mf < 4; ++mf)
      afr[mf] = __builtin_bit_cast(bf8, *(const uint4*)(&Al[(w * 64 + mf * 16 + r16) * 40 + kb]));
    #pragma unroll
    for (int nf = 0; nf < 4; ++nf)
      bfr[nf] = __builtin_bit_cast(bf8, *(const uint4*)(&Bl[(nf * 16 + r16) * 40 + kb]));
    #pragma unroll
    for (int mf = 0; mf < 4; ++mf)
      #pragma unroll
      for (int nf = 0; nf < 4; ++nf)
        acc[mf][nf] = __builtin_amdgcn_mfma_f32_16x16x32_bf16(afr[mf], bfr[nf], acc[mf][nf], 0, 0, 0);
    __syncthreads();
  }
  #pragma unroll
  for (int nf = 0; nf < 4; ++nf) {
    int col = n0 + nf * 16 + r16;
    float bv = bias[col];
    #pragma unroll
    for (int mf = 0; mf < 4; ++mf) {
      int row0 = w * 64 + mf * 16 + (l >> 4) * 4;
      #pragma unroll
      for (int r = 0; r < 4; ++r)
        out[(long)(row0 + r) * N + col] = acc[mf][nf][r] + bv;
    }
  }
}

// ---- kernel 3: blocks 0..255: 128-step rollout (f16 dot2, 1 barrier/step);
//                blocks 256..513: x_gt/z_gt GEMM ----
__global__ __launch_bounds__(512, 2) void k_seqgt(const float* __restrict__ Act,
                                                  const float* __restrict__ Bm,
                                                  const float* __restrict__ u_fut,
                                                  const float* __restrict__ x_init,
                                                  const float* __restrict__ x_fut,
                                                  const float* __restrict__ We,
                                                  const float* __restrict__ be,
                                                  float* __restrict__ zt,
                                                  float* __restrict__ x_gt,
                                                  float* __restrict__ z_gt) {
  extern __shared__ __align__(16) char smem[];
  int t = threadIdx.x;
  if (blockIdx.x < 256) {
    // ---------------- scan branch ----------------
    u16* zxh = (u16*)(smem);           // [2][256] f16 z broadcast, double-buffered
    u16* ulh = (u16*)(smem + 1024);    // [128*32] f16 u_fut staged
    int b = blockIdx.x;
    int w = t >> 6, l = t & 63;
    int i = w * 32 + (l >> 1);         // output row owned by this lane pair
    int jh = l & 1;                    // which j-half this lane sums
    int j0 = jh * 128;
    const float* A = Act + (size_t)b * 65536;
    // m_pk[q] = {DT*A[i][j0+2q], DT*A[i][j0+2q+1]}  (64 VGPRs)
    h2 m_pk[64];
    {
      const float* rp = A + (size_t)i * 256 + j0;
      #pragma unroll
      for (int q = 0; q < 32; ++q) {
        float4 v = *(const float4*)(rp + q * 4);
        m_pk[q * 2]     = pkh(v.x * DT_C, v.y * DT_C);
        m_pk[q * 2 + 1] = pkh(v.z * DT_C, v.w * DT_C);
      }
    }
    // stage u_fut[b] as f16 (8 KB)
    {
      const float* ub = u_fut + (size_t)b * 4096;
      float4 v0 = *(const float4*)(ub + t * 8);
      float4 v1 = *(const float4*)(ub + t * 8 + 4);
      uint4 st;
      st.x = __builtin_bit_cast(unsigned, pkh(v0.x, v0.y));
      st.y = __builtin_bit_cast(unsigned, pkh(v0.z, v0.w));
      st.z = __builtin_bit_cast(unsigned, pkh(v1.x, v1.y));
      st.w = __builtin_bit_cast(unsigned, pkh(v1.z, v1.w));
      *(uint4*)(&ulh[t * 8]) = st;
    }
    // B row (packed f16) — used by odd lanes for c
    h2 br_pk[16];
    {
      const float* bp = Bm + (size_t)b * 8192 + (size_t)i * 32;
      #pragma unroll
      for (int q = 0; q < 8; ++q) {
        float4 v = *(const float4*)(bp + q * 4);
        br_pk[q * 2]     = pkh(v.x, v.y);
        br_pk[q * 2 + 1] = pkh(v.z, v.w);
      }
    }
    __syncthreads();   // ulh visible
    // z0 = We^T x_init + be (threads t<256 own output t), write f32 + f16 buf0
    if (t < 256) {
      float z = be[t];
      const float* xi = x_init + b * 64;
      #pragma unroll 8
      for (int s = 0; s < 64; ++s) z += xi[s] * We[s * 256 + t];
      zt[(size_t)b * 33024 + t] = z;
      __fp16 zh = (__fp16)z;
      zxh[t] = __builtin_bit_cast(u16, zh);
    }
    // c_0 on odd lanes (ulh ready after barrier above)
    float cnext = 0.f;
    if (jh) {
      float cc = 0.f;
      #pragma unroll
      for (int q = 0; q < 4; ++q) {
        uint4 uu = *(const uint4*)(&ulh[q * 8]);
        cc = __builtin_amdgcn_fdot2(br_pk[q * 4 + 0], ash2(uu.x), cc, false);
        cc = __builtin_amdgcn_fdot2(br_pk[q * 4 + 1], ash2(uu.y), cc, false);
        cc = __builtin_amdgcn_fdot2(br_pk[q * 4 + 2], ash2(uu.z), cc, false);
        cc = __builtin_amdgcn_fdot2(br_pk[q * 4 + 3], ash2(uu.w), cc, false);
      }
      cnext = cc;
    }
    wg_barrier();      // zxh buf0 visible
    float zreg = 0.f;
    if (!jh) {
      __fp16 zh = __builtin_bit_cast(__fp16, zxh[i]);
      zreg = (float)zh;
    }
    float* ztb = zt + (size_t)b * 33024;
    for (int k = 0; k < 128; ++k) {
      const u16* zb = zxh + (k & 1) * 256 + j0;
      float a0 = 0.f, a1 = 0.f, a2 = 0.f, a3 = 0.f;
      #pragma unroll
      for (int q = 0; q < 16; ++q) {
        uint4 zz = *(const uint4*)(zb + q * 8);
        a0 = __builtin_amdgcn_fdot2(m_pk[q * 4 + 0], ash2(zz.x), a0, false);
        a1 = __builtin_amdgcn_fdot2(m_pk[q * 4 + 1], ash2(zz.y), a1, false);
        a2 = __builtin_amdgcn_fdot2(m_pk[q * 4 + 2], ash2(zz.z), a2, false);
        a3 = __builtin_amdgcn_fdot2(m_pk[q * 4 + 3], ash2(zz.w), a3, false);
      }
      float s = (a0 + a1) + (a2 + a3);
      s += __shfl_xor(s, 1, 64);                 // total M z over all 256 j
      float c = __shfl_xor(cnext, 1, 64);        // even lane receives c_k
      if (!jh) {
        float nz = zreg + s + c;
        zreg = nz;
        ztb[(size_t)(k + 1) * 256 + i] = nz;
        __fp16 zh = (__fp16)nz;
        zxh[((k + 1) & 1) * 256 + i] = __builtin_bit_cast(u16, zh);
      } else if (k < 127) {
        const u16* up = ulh + (size_t)(k + 1) * 32;
        float cc = 0.f;
        #pragma unroll
        for (int q = 0; q < 4; ++q) {
          uint4 uu = *(const uint4*)(up + q * 8);
          cc = __builtin_amdgcn_fdot2(br_pk[q * 4 + 0], ash2(uu.x), cc, false);
          cc = __builtin_amdgcn_fdot2(br_pk[q * 4 + 1], ash2(uu.y), cc, false);
          cc = __builtin_amdgcn_fdot2(br_pk[q * 4 + 2], ash2(uu.z), cc, false);
          cc = __builtin_amdgcn_fdot2(br_pk[q * 4 + 3], ash2(uu.w), cc, false);
        }
        cnext = cc;
      }
      wg_barrier();
    }
  } else {
    // ---------------- gt branch: assemble x_gt, z_gt = x_gt @ We + be ----------------
    u16* Al = (u16*)(smem);          // [128*40]
    u16* Bl = (u16*)(smem + 10240);  // [256*40]
    long r0 = (long)(blockIdx.x - 256) * 128;
    int w = t >> 6, l = t & 63, r16 = l & 15, kb = (l >> 4) * 8;
    int wm = w >> 2, wn = w & 3;
    f32x4 acc[4][4];
    #pragma unroll
    for (int i = 0; i < 4; ++i)
      #pragma unroll
      for (int j = 0; j < 4; ++j) acc[i][j] = f32x4{0.f, 0.f, 0.f, 0.f};
    for (int kk = 0; kk < 2; ++kk) {
      int k0 = kk * 32;
      {
        int row = t >> 2, kq = t & 3;
        long gr = r0 + row;
        unsigned bb = (unsigned)gr / 129u;
        unsigned rr = (unsigned)gr - bb * 129u;
        const float* src = (rr == 0) ? (x_init + (size_t)bb * 64)
                                     : (x_fut + ((size_t)bb * 128 + (rr - 1)) * 64);
        float4 v0 = *(const float4*)(src + k0 + kq * 8);
        float4 v1 = *(const float4*)(src + k0 + kq * 8 + 4);
        *(float4*)(&x_gt[gr * 64 + k0 + kq * 8]) = v0;
        *(float4*)(&x_gt[gr * 64 + k0 + kq * 8 + 4]) = v1;
        u16 tmp[8];
        tmp[0] = f2bf(v0.x); tmp[1] = f2bf(v0.y); tmp[2] = f2bf(v0.z); tmp[3] = f2bf(v0.w);
        tmp[4] = f2bf(v1.x); tmp[5] = f2bf(v1.y); tmp[6] = f2bf(v1.z); tmp[7] = f2bf(v1.w);
        *(uint4*)(&Al[row * 40 + kq * 8]) = *(uint4*)(tmp);
      }
      {
        int n = t & 255, kh = (t >> 8) * 16;
        #pragma unroll
        for (int kp = 0; kp < 8; ++kp) {
          int k = k0 + kh + kp * 2;
          float f0 = We[(size_t)k * 256 + n];
          float f1 = We[(size_t)(k + 1) * 256 + n];
          *(unsigned*)(&Bl[n * 40 + kh + kp * 2]) = ((unsigned)f2bf(f1) << 16) | (unsigned)f2bf(f0);
        }
      }
      __syncthreads();
      bf8 af[4], bfv[4];
      #pragma unroll
      for (int mf = 0; mf < 4; ++mf)
        af[mf] = __builtin_bit_cast(bf8, *(const uint4*)(&Al[(wm * 64 + mf * 16 + r16) * 40 + kb]));
      #pragma unroll
      for (int nf = 0; nf < 4; ++nf)
        bfv[nf] = __builtin_bit_cast(bf8, *(const uint4*)(&Bl[(wn * 64 + nf * 16 + r16) * 40 + kb]));
      #pragma unroll
      for (int mf = 0; mf < 4; ++mf)
        #pragma unroll
        for (int nf = 0; nf < 4; ++nf)
          acc[mf][nf] = __builtin_amdgcn_mfma_f32_16x16x32_bf16(af[mf], bfv[nf], acc[mf][nf], 0, 0, 0);
      __syncthreads();
    }
    #pragma unroll
    for (int nf = 0; nf < 4; ++nf) {
      int c = wn * 64 + nf * 16 + r16;
      float bv = be[c];
      #pragma unroll
      for (int mf = 0; mf < 4; ++mf) {
        long row0 = r0 + wm * 64 + mf * 16 + (l >> 4) * 4;
        #pragma unroll
        for (int r = 0; r < 4; ++r)
          z_gt[(row0 + r) * 256 + c] = acc[mf][nf][r] + bv;
      }
    }
  }
}

// ---- kernel 4: x_traj = z@Wd+bd; z_re = bf16(x_traj)@We+be (two-phase) ----
__global__ __launch_bounds__(512) void k_decenc2(const float* __restrict__ z,
                                                 const float* __restrict__ Wd,
                                                 const float* __restrict__ bd,
                                                 const float* __restrict__ We,
                                                 const float* __restrict__ be,
                                                 float* __restrict__ x_traj,
                                                 float* __restrict__ z_re) {
  __shared__ __align__(16) char sm[55296];
  u16* Al  = (u16*)(sm);           // [128*40] phase1 (dead in phase2)
  u16* Bl  = (u16*)(sm + 10240);   // [64*40]  phase1 (dead in phase2)
  u16* Xl  = (u16*)(sm);           // [128*72] phase2 x-tile (overlays Al+Bl)
  u16* Bl2 = (u16*)(sm + 18432);   // [256*72] We staged once
  int t = threadIdx.x;
  long r0 = (long)blockIdx.x * 128;
  int w = t >> 6, l = t & 63, r16 = l & 15, kb = (l >> 4) * 8;
  int wm = w >> 2, wn = w & 3;
  {
    int n = t & 255, kh = (t >> 8) * 32;
    #pragma unroll
    for (int kp = 0; kp < 16; ++kp) {
      int k = kh + kp * 2;
      float f0 = We[(size_t)k * 256 + n];
      float f1 = We[(size_t)(k + 1) * 256 + n];
      *(unsigned*)(&Bl2[n * 72 + kh + kp * 2]) = ((unsigned)f2bf(f1) << 16) | (unsigned)f2bf(f0);
    }
  }
  f32x4 acc1[4];
  #pragma unroll
  for (int i = 0; i < 4; ++i) acc1[i] = f32x4{0.f, 0.f, 0.f, 0.f};
  for (int kk = 0; kk < 8; ++kk) {
    int k0 = kk * 32;
    {
      int row = t >> 2, kq = t & 3;
      const float* zs = z + (r0 + row) * 256 + k0 + kq * 8;
      float4 v0 = *(const float4*)(zs);
      float4 v1 = *(const float4*)(zs + 4);
      u16 tmp[8];
      tmp[0] = f2bf(v0.x); tmp[1] = f2bf(v0.y); tmp[2] = f2bf(v0.z); tmp[3] = f2bf(v0.w);
      tmp[4] = f2bf(v1.x); tmp[5] = f2bf(v1.y); tmp[6] = f2bf(v1.z); tmp[7] = f2bf(v1.w);
      *(uint4*)(&Al[row * 40 + kq * 8]) = *(uint4*)(tmp);
    }
    {
      int c = t & 63, kp0 = (t >> 6) * 2;
      #pragma unroll
      for (int r2 = 0; r2 < 2; ++r2) {
        int kp = kp0 + r2;
        int k = k0 + kp * 2;
        float f0 = Wd[(size_t)k * 64 + c];
        float f1 = Wd[(size_t)(k + 1) * 64 + c];
        *(unsigned*)(&Bl[c * 40 + kp * 2]) = ((unsigned)f2bf(f1) << 16) | (unsigned)f2bf(f0);
      }
    }
    __syncthreads();
    bf8 af[4];
    #pragma unroll
    for (int mf = 0; mf < 4; ++mf)
      af[mf] = __builtin_bit_cast(bf8, *(const uint4*)(&Al[(wm * 64 + mf * 16 + r16) * 40 + kb]));
    bf8 bf1 = __builtin_bit_cast(bf8, *(const uint4*)(&Bl[(wn * 16 + r16) * 40 + kb]));
    #pragma unroll
    for (int mf = 0; mf < 4; ++mf)
      acc1[mf] = __builtin_amdgcn_mfma_f32_16x16x32_bf16(af[mf], bf1, acc1[mf], 0, 0, 0);
    __syncthreads();
  }
  {
    int c = wn * 16 + r16;
    float bv = bd[c];
    #pragma unroll
    for (int mf = 0; mf < 4; ++mf) {
      int rowb = wm * 64 + mf * 16 + (l >> 4) * 4;
      #pragma unroll
      for (int r = 0; r < 4; ++r) {
        float val = acc1[mf][r] + bv;
        x_traj[(r0 + rowb + r) * 64 + c] = val;
        Xl[(rowb + r) * 72 + c] = f2bf(val);
      }
    }
  }
  __syncthreads();
  f32x4 acc2[4][4];
  #pragma unroll
  for (int i = 0; i < 4; ++i)
    #pragma unroll
    for (int j = 0; j < 4; ++j) acc2[i][j] = f32x4{0.f, 0.f, 0.f, 0.f};
  #pragma unroll
  for (int kk = 0; kk < 2; ++kk) {
    int k0 = kk * 32;
    bf8 af[4], bfv[4];
    #pragma unroll
    for (int mf = 0; mf < 4; ++mf)
      af[mf] = __builtin_bit_cast(bf8, *(const uint4*)(&Xl[(wm * 64 + mf * 16 + r16) * 72 + k0 + kb]));
    #pragma unroll
    for (int nf = 0; nf < 4; ++nf)
      bfv[nf] = __builtin_bit_cast(bf8, *(const uint4*)(&Bl2[(wn * 64 + nf * 16 + r16) * 72 + k0 + kb]));
    #pragma unroll
    for (int mf = 0; mf < 4; ++mf)
      #pragma unroll
      for (int nf = 0; nf < 4; ++nf)
        acc2[mf][nf] = __builtin_amdgcn_mfma_f32_16x16x32_bf16(af[mf], bfv[nf], acc2[mf][nf], 0, 0, 0);
  }
  #pragma unroll
  for (int nf = 0; nf < 4; ++nf) {
    int c = wn * 64 + nf * 16 + r16;
    float bv = be[c];
    #pragma unroll
    for (int mf = 0; mf < 4; ++mf) {
      long row0 = r0 + wm * 64 + mf * 16 + (l >> 4) * 4;
      #pragma unroll
      for (int r = 0; r < 4; ++r)
        z_re[(row0 + r) * 256 + c] = acc2[mf][nf][r] + bv;
    }
  }
}

extern "C" void kernel_launch(void* const* d_in, const int* in_sizes, int n_in,
                              void* d_out, int out_size, void* d_ws, size_t ws_size,
                              hipStream_t stream) {
  const float* xh     = (const float*)d_in[0];
  const float* uh     = (const float*)d_in[1];
  const float* x_init = (const float*)d_in[2];
  const float* x_fut  = (const float*)d_in[3];
  const float* u_fut  = (const float*)d_in[4];
  const float* Wc = (const float*)d_in[6];
  const float* bc = (const float*)d_in[7];
  const float* WA = (const float*)d_in[8];
  const float* bA = (const float*)d_in[9];
  const float* WB = (const float*)d_in[10];
  const float* bB = (const float*)d_in[11];
  const float* We = (const float*)d_in[12];
  const float* be = (const float*)d_in[13];
  const float* Wd = (const float*)d_in[14];
  const float* bd = (const float*)d_in[15];

  float* out    = (float*)d_out;
  float* z_traj = out;                 // [256,129,256]
  float* x_traj = out + 8454144;       // [256,129,64]
  float* A_ct   = out + 10567680;      // [256,256,256]
  float* B_mat  = out + 27344896;      // [256,256,32]
  float* z_re   = out + 29442048;      // [256,129,256]
  float* x_gt   = out + 37896192;      // [256,129,64]
  float* z_gt   = out + 40009728;      // [256,129,256]

  u16* h_bf = (u16*)d_ws;              // 256KB

  hipLaunchKernelGGL(k_ctxt,    dim3(256),  dim3(512), 0,     stream, xh, uh, Wc, bc, h_bf);
  hipLaunchKernelGGL(k_heads,   dim3(1152), dim3(256), 0,     stream, h_bf, WA, bA, WB, bB, A_ct, B_mat);
  hipLaunchKernelGGL(k_seqgt,   dim3(514),  dim3(512), 30720, stream, A_ct, B_mat, u_fut, x_init, x_fut,
                     We, be, z_traj, x_gt, z_gt);
  hipLaunchKernelGGL(k_decenc2, dim3(258),  dim3(512), 0,     stream, z_traj, Wd, bd, We, be, x_traj, z_re);
}